// Round 12
// baseline (343.513 us; speedup 1.0000x reference)
//
#include <hip/hip_runtime.h>
#include <cstdint>
#include <cstddef>

#define NPTS 8192
#define NBATCH 4
#define KNN 10
#define NPAIR 45
#define TILE 512
#define MARGIN 12
#define QSZ 96
#define DRAIN_AT 16
#define EPSD 1e-6
#define GRID 32
#define NCELL (GRID*GRID*GRID)
#define HCELL 0.3f
#define ORG (-4.8f)

__device__ __constant__ int dCOMB_A[NPAIR] = {
  0,0,0,0,0,0,0,0,0, 1,1,1,1,1,1,1,1, 2,2,2,2,2,2,2,
  3,3,3,3,3,3, 4,4,4,4,4, 5,5,5,5, 6,6,6, 7,7, 8};
__device__ __constant__ int dCOMB_B[NPAIR] = {
  1,2,3,4,5,6,7,8,9, 2,3,4,5,6,7,8,9, 3,4,5,6,7,8,9,
  4,5,6,7,8,9, 5,6,7,8,9, 6,7,8,9, 7,8,9, 8,9, 9};

__device__ __forceinline__ void cell_coords(float x, float y, float z,
                                            int& cx, int& cy, int& cz) {
  cx = (int)floorf((x - ORG) * (1.0f / HCELL));
  cy = (int)floorf((y - ORG) * (1.0f / HCELL));
  cz = (int)floorf((z - ORG) * (1.0f / HCELL));
  cx = min(max(cx, 0), GRID - 1);
  cy = min(max(cy, 0), GRID - 1);
  cz = min(max(cz, 0), GRID - 1);
}

// ---------------- grid build ----------------
__global__ __launch_bounds__(256) void zero_cells(uint32_t* ccur) {
  int i = blockIdx.x * 256 + threadIdx.x;
  if (i < NBATCH * NCELL) ccur[i] = 0;
}

__global__ __launch_bounds__(256) void grid_count(const float* __restrict__ src,
                                                  uint32_t* ccur) {
  int i = blockIdx.x * 256 + threadIdx.x;          // 0..32767
  int b = i >> 13, p = i & (NPTS - 1);
  const float* sb = src + (size_t)b * 3 * NPTS;
  int cx, cy, cz;
  cell_coords(sb[p], sb[NPTS + p], sb[2 * NPTS + p], cx, cy, cz);
  atomicAdd(&ccur[b * NCELL + ((cz * GRID) + cy) * GRID + cx], 1u);
}

// One block per batch: exclusive scan counts -> cstart (NCELL+1) and cursor copy.
__global__ __launch_bounds__(1024) void grid_scan(uint32_t* ccur,
                                                  uint32_t* __restrict__ cstart) {
  __shared__ uint32_t swv[16];
  const int b = blockIdx.x;
  const int tid = threadIdx.x, lane = tid & 63, wid = tid >> 6;
  const uint32_t base = b * NCELL;
  uint32_t running = 0;
  for (int chunk = 0; chunk < NCELL / 8192; ++chunk) {
    int i0 = chunk * 8192 + tid * 8;
    uint32_t v[8], ts = 0;
#pragma unroll
    for (int k = 0; k < 8; ++k) { v[k] = ccur[base + i0 + k]; ts += v[k]; }
    uint32_t x = ts;
#pragma unroll
    for (int off = 1; off < 64; off <<= 1) {
      uint32_t y = __shfl_up(x, off, 64);
      if (lane >= off) x += y;
    }
    if (lane == 63) swv[wid] = x;
    __syncthreads();
    uint32_t wpre = 0, bsum = 0;
    for (int w = 0; w < 16; ++w) { uint32_t s = swv[w]; bsum += s; if (w < wid) wpre += s; }
    uint32_t excl = running + wpre + (x - ts);
#pragma unroll
    for (int k = 0; k < 8; ++k) {
      cstart[b * (NCELL + 1) + i0 + k] = excl;
      ccur[base + i0 + k] = excl;                 // cursor for scatter
      excl += v[k];
    }
    running += bsum;
    __syncthreads();
  }
  if (tid == 0) cstart[b * (NCELL + 1) + NCELL] = running;   // = NPTS
}

__global__ __launch_bounds__(256) void grid_scatter(const float* __restrict__ src,
                                                    uint32_t* ccur,
                                                    float4* __restrict__ pts,
                                                    uint32_t* __restrict__ oidx) {
  int i = blockIdx.x * 256 + threadIdx.x;
  int b = i >> 13, p = i & (NPTS - 1);
  const float* sb = src + (size_t)b * 3 * NPTS;
  float x = sb[p], y = sb[NPTS + p], z = sb[2 * NPTS + p];
  int cx, cy, cz;
  cell_coords(x, y, z, cx, cy, cz);
  uint32_t pos = atomicAdd(&ccur[b * NCELL + ((cz * GRID) + cy) * GRID + cx], 1u);
  pts[(b << 13) + pos]  = make_float4(x, y, z, x * x + y * y + z * z);
  oidx[(b << 13) + pos] = (uint32_t)p;
}

// ---------------- main: grid-accelerated wave-per-point ----------------
__global__ __launch_bounds__(256) void gfm_grid(const float* __restrict__ src,
                                                const float* __restrict__ tgt,
                                                const float4* __restrict__ pts,
                                                const uint32_t* __restrict__ oidx,
                                                const uint32_t* __restrict__ cstart,
                                                float* __restrict__ mean_out) {
  __shared__ uint64_t sqq[4][QSZ];
  __shared__ uint64_t stp[4][MARGIN];
  __shared__ double lsA[4][NPAIR];
  __shared__ double lsB[4][NPAIR];
  __shared__ double smed[4];
  __shared__ double ssum[4][KNN];
  __shared__ double rd2[4][MARGIN];
  __shared__ int    rid[4][MARGIN];
  __shared__ int    snbr[4][KNN];

  const int tid  = threadIdx.x;
  const int wv   = tid >> 6;
  const int lane = tid & 63;
  const int b    = blockIdx.x >> 11;
  const int n    = ((blockIdx.x & 2047) << 2) | wv;

  const float* __restrict__ sb = src + (size_t)b * 3 * NPTS;
  const float* __restrict__ tb = tgt + (size_t)b * 3 * NPTS;
  const float4* __restrict__ ppts = pts + ((size_t)b << 13);
  const uint32_t* __restrict__ poid = oidx + ((size_t)b << 13);
  const uint32_t* __restrict__ cs = cstart + (size_t)b * (NCELL + 1);

  const float xnf = sb[n], ynf = sb[NPTS + n], znf = sb[2 * NPTS + n];
  const float sqnf = xnf * xnf + ynf * ynf + znf * znf;

  int qcx, qcy, qcz;
  cell_coords(xnf, ynf, znf, qcx, qcy, qcz);
  // distance from query to its (clamped) cell box — ~0 unless clamped
  float lox = ORG + qcx * HCELL, loy = ORG + qcy * HCELL, loz = ORG + qcz * HCELL;
  float dqx = fmaxf(fmaxf(lox - xnf, xnf - (lox + HCELL)), 0.0f);
  float dqy = fmaxf(fmaxf(loy - ynf, ynf - (loy + HCELL)), 0.0f);
  float dqz = fmaxf(fmaxf(loz - znf, znf - (loz + HCELL)), 0.0f);
  const float deltaq = sqrtf(dqx * dqx + dqy * dqy + dqz * dqz);

  if (lane < MARGIN) stp[wv][lane] = ~0ull;
  __builtin_amdgcn_wave_barrier();
  float tau_f = __builtin_inff();
  int qn = 0;

  auto drain = [&]() {
    if (lane < MARGIN) sqq[wv][qn + lane] = stp[wv][lane];
    __builtin_amdgcn_wave_barrier();
    const int tot = qn + MARGIN;
    uint64_t k0 = (lane < tot) ? sqq[wv][lane] : ~0ull;
    uint64_t k1 = (lane + 64 < tot) ? sqq[wv][lane + 64] : ~0ull;
    int r0 = 0, r1 = 0;
    for (int m = 0; m < tot; ++m) {
      uint64_t km = sqq[wv][m];
      r0 += (km < k0);
      r1 += (km < k1);
    }
    __builtin_amdgcn_wave_barrier();
    if (lane < tot && r0 < MARGIN) stp[wv][r0] = k0;
    if (lane + 64 < tot && r1 < MARGIN) stp[wv][r1] = k1;
    __builtin_amdgcn_wave_barrier();
    tau_f = __uint_as_float((uint32_t)(stp[wv][MARGIN - 1] >> 32));
    qn = 0;
  };

  // ---- ring walk ----
  for (int r = 0; r < GRID; ++r) {
    if (r >= 2) {
      float mrg = (float)(r - 1) * HCELL - deltaq;
      if (mrg > 0.0f && mrg * mrg > tau_f * 1.0001f) break;
    }
    const int side = 2 * r + 1, s2 = side * side, ncube = s2 * side;
    for (int base = 0; base < ncube; base += 64) {
      int fi = base + lane;
      uint32_t st = 0, cnt = 0;
      if (fi < ncube) {
        int dz = fi / s2; int rem = fi - dz * s2;
        int dy = rem / side; int dx = rem - dy * side;
        dx -= r; dy -= r; dz -= r;
        int md = max(abs(dx), max(abs(dy), abs(dz)));
        int cx = qcx + dx, cy = qcy + dy, cz = qcz + dz;
        bool ok = (md == r) && cx >= 0 && cx < GRID && cy >= 0 && cy < GRID &&
                  cz >= 0 && cz < GRID;
        if (ok) {
          uint32_t c = (uint32_t)(((cz * GRID) + cy) * GRID + cx);
          st = cs[c];
          cnt = cs[c + 1] - st;
        }
      }
      uint64_t mask = __ballot(cnt > 0);
      while (mask) {
        int l = __ffsll((unsigned long long)mask) - 1;
        mask &= mask - 1;
        uint32_t stc = (uint32_t)__shfl((int)st, l, 64);
        uint32_t cnc = (uint32_t)__shfl((int)cnt, l, 64);
        for (uint32_t sub = 0; sub < cnc; sub += 64) {
          uint32_t ii = sub + (uint32_t)lane;
          bool act = ii < cnc;
          bool pred = false;
          float d2 = 0.0f;
          uint32_t pos = 0;
          if (act) {
            pos = stc + ii;
            float4 c4 = ppts[pos];
            float dot = fmaf(xnf, c4.x, fmaf(ynf, c4.y, znf * c4.z));
            d2 = fmaxf(fmaf(-2.0f, dot, sqnf + c4.w), 0.0f);
            pred = d2 <= tau_f;
          }
          uint64_t m2 = __ballot(pred);
          if (m2) {
            int below = __builtin_amdgcn_mbcnt_hi((uint32_t)(m2 >> 32),
                         __builtin_amdgcn_mbcnt_lo((uint32_t)m2, 0));
            if (pred) {
              uint64_t key = ((uint64_t)__float_as_uint(d2) << 32) |
                             (uint64_t)poid[pos];
              sqq[wv][qn + below] = key;
            }
            __builtin_amdgcn_wave_barrier();
            qn += __popcll(m2);
            if (qn >= DRAIN_AT) drain();
          }
        }
      }
    }
  }
  if (qn > 0) drain();

  if (lane < MARGIN) rid[wv][lane] = (int)(uint32_t)(stp[wv][lane] & 0xFFFFFFFFull);
  __syncthreads();

  // ---- exact f64 re-rank of 12 candidates (identical to R11) ----
  const double xn = (double)xnf, yn = (double)ynf, zn = (double)znf;
  const double sqn = xn * xn + yn * yn + zn * zn;
  double myd2 = 0.0;
  int myid = 0;
  if (lane < MARGIN) {
    myid = rid[wv][lane];
    double gx = (double)sb[myid], gy = (double)sb[NPTS + myid], gz = (double)sb[2 * NPTS + myid];
    double gsq = gx * gx + gy * gy + gz * gz;
    double dot = xn * gx + yn * gy + zn * gz;
    double d2 = sqn + gsq - 2.0 * dot;
    if (d2 < 0.0) d2 = 0.0;
    myd2 = d2;
    rd2[wv][lane] = d2;
  }
  __syncthreads();
  if (lane < MARGIN) {
    int rk = 0;
    for (int m = 0; m < MARGIN; ++m) {
      double dm = rd2[wv][m];
      rk += (dm < myd2) || (dm == myd2 && rid[wv][m] < myid);
    }
    if (rk < KNN) snbr[wv][rk] = myid;
  }
  __syncthreads();

  // ---- phase 2 (identical to rounds 8-11) ----
  const double txn = (double)tb[n], tyn = (double)tb[NPTS + n], tzn = (double)tb[2 * NPTS + n];
  const int p = lane;
  double loss = 0.0, reg = 0.0;
  if (p < NPAIR) {
    int g1 = snbr[wv][dCOMB_A[p]];
    int g2 = snbr[wv][dCOMB_B[p]];

    double ax = (double)sb[g1] - xn, ay = (double)sb[NPTS + g1] - yn, az = (double)sb[2 * NPTS + g1] - zn;
    double bx = (double)sb[g2] - xn, by = (double)sb[NPTS + g2] - yn, bz = (double)sb[2 * NPTS + g2] - zn;
    double cx = ay * bz - az * by;
    double cy = az * bx - ax * bz;
    double cz = ax * by - ay * bx;
    double s  = cx * cx + cy * cy + cz * cz;
    double a_s = (s > 0.0) ? 0.5 * sqrt(s) : 0.0;

    double ux = (double)tb[g1] - txn, uy = (double)tb[NPTS + g1] - tyn, uz = (double)tb[2 * NPTS + g1] - tzn;
    double vx = (double)tb[g2] - txn, vy = (double)tb[NPTS + g2] - tyn, vz = (double)tb[2 * NPTS + g2] - tzn;
    double wx = uy * vz - uz * vy;
    double wy = uz * vx - ux * vz;
    double wz = ux * vy - uy * vx;
    double t2 = wx * wx + wy * wy + wz * wz;
    double a_t = (t2 > 0.0) ? 0.5 * sqrt(t2) : 0.0;

    double ate = a_t + EPSD;
    double d   = a_s - ate;
    double numer = (EPSD * EPSD + EPSD * EPSD) + d * d;
    double denom = (EPSD + EPSD) + (a_s + ate);
    loss = numer / denom;
    reg  = sqrt(numer);
    lsA[wv][p] = loss;
  }
  __syncthreads();

  if (p < NPAIR) {
    int rk = 0;
    for (int m = 0; m < NPAIR; ++m) {
      double lm = lsA[wv][m];
      rk += (lm < loss) || (lm == loss && m < p);
    }
    lsB[wv][rk] = loss;
  }
  __syncthreads();
  double tot2 = 0.0;
  if (p < NPAIR) {
    tot2 = lsB[wv][p] + 0.1 * reg;
    lsA[wv][p] = tot2;
  }
  __syncthreads();
  if (p < NPAIR) {
    int rk = 0;
    for (int m = 0; m < NPAIR; ++m) {
      double tm = lsA[wv][m];
      rk += (tm < tot2) || (tm == tot2 && m < p);
    }
    if (rk == (NPAIR - 1) / 2) smed[wv] = tot2;
  }
  __syncthreads();
  double med = smed[wv];
  if (p < KNN) {
    double t = (tot2 > 3.0 * med) ? 0.0 : tot2;
    ssum[wv][p] = sqrt(t + EPSD);
  }
  __syncthreads();
  if (lane == 0) {
    double sum = 0.0;
#pragma unroll
    for (int q = 0; q < KNN; ++q) sum += ssum[wv][q];
    mean_out[b * NPTS + n] = (float)(sum / 10.0);
  }
}

// ---------------- fallback: R11 full-scan kernels ----------------
__global__ __launch_bounds__(256) void pack_pts(const float* __restrict__ src,
                                                float4* __restrict__ pk) {
  int i = blockIdx.x * 256 + threadIdx.x;
  int b = i >> 13, p = i & (NPTS - 1);
  const float* sb = src + (size_t)b * 3 * NPTS;
  float x = sb[p], y = sb[NPTS + p], z = sb[2 * NPTS + p];
  pk[i] = make_float4(x, y, z, x * x + y * y + z * z);
}

template <bool PACKED>
__global__ __launch_bounds__(256) void gfm_wave(const float* __restrict__ src,
                                                const float* __restrict__ tgt,
                                                const float4* __restrict__ pk,
                                                float* __restrict__ mean_out) {
  __shared__ float4   s4[TILE];
  __shared__ uint64_t sqq[4][QSZ];
  __shared__ uint64_t stp[4][MARGIN];
  __shared__ double lsA[4][NPAIR];
  __shared__ double lsB[4][NPAIR];
  __shared__ double smed[4];
  __shared__ double ssum[4][KNN];
  __shared__ double rd2[4][MARGIN];
  __shared__ int    rid[4][MARGIN];
  __shared__ int    snbr[4][KNN];

  const int tid  = threadIdx.x;
  const int wv   = tid >> 6;
  const int lane = tid & 63;
  const int b    = blockIdx.x >> 11;
  const int n    = ((blockIdx.x & 2047) << 2) | wv;

  const float* __restrict__ sb = src + (size_t)b * 3 * NPTS;
  const float* __restrict__ tb = tgt + (size_t)b * 3 * NPTS;

  const float xnf = sb[n], ynf = sb[NPTS + n], znf = sb[2 * NPTS + n];
  const float sqnf = xnf * xnf + ynf * ynf + znf * znf;

  if (lane < MARGIN) stp[wv][lane] = ~0ull;
  __builtin_amdgcn_wave_barrier();
  float tau_f = __builtin_inff();
  int qn = 0;

  auto drain = [&]() {
    if (lane < MARGIN) sqq[wv][qn + lane] = stp[wv][lane];
    __builtin_amdgcn_wave_barrier();
    const int tot = qn + MARGIN;
    uint64_t k0 = (lane < tot) ? sqq[wv][lane] : ~0ull;
    uint64_t k1 = (lane + 64 < tot) ? sqq[wv][lane + 64] : ~0ull;
    int r0 = 0, r1 = 0;
    for (int m = 0; m < tot; ++m) {
      uint64_t km = sqq[wv][m];
      r0 += (km < k0);
      r1 += (km < k1);
    }
    __builtin_amdgcn_wave_barrier();
    if (lane < tot && r0 < MARGIN) stp[wv][r0] = k0;
    if (lane + 64 < tot && r1 < MARGIN) stp[wv][r1] = k1;
    __builtin_amdgcn_wave_barrier();
    tau_f = __uint_as_float((uint32_t)(stp[wv][MARGIN - 1] >> 32));
    qn = 0;
  };

  for (int t0 = 0; t0 < NPTS; t0 += TILE) {
    __syncthreads();
    if (PACKED) {
      const float4* __restrict__ g = pk + (size_t)b * NPTS + t0;
#pragma unroll
      for (int r = 0; r < TILE / 256; ++r) {
        int i = tid + r * 256;
        s4[i] = g[i];
      }
    } else {
#pragma unroll
      for (int r = 0; r < TILE / 256; ++r) {
        int i = tid + r * 256;
        float x = sb[t0 + i], y = sb[NPTS + t0 + i], z = sb[2 * NPTS + t0 + i];
        s4[i] = make_float4(x, y, z, x * x + y * y + z * z);
      }
    }
    __syncthreads();
#pragma unroll 2
    for (int r = 0; r < TILE / 64; ++r) {
      int j = lane + (r << 6);
      float4 c = s4[j];
      float dot = fmaf(xnf, c.x, fmaf(ynf, c.y, znf * c.z));
      float d2 = fmaxf(fmaf(-2.0f, dot, sqnf + c.w), 0.0f);
      bool pred = d2 <= tau_f;
      uint64_t mask = __ballot(pred);
      if (mask) {
        uint64_t key = ((uint64_t)__float_as_uint(d2) << 32) | (uint32_t)(t0 + j);
        int below = __builtin_amdgcn_mbcnt_hi((uint32_t)(mask >> 32),
                     __builtin_amdgcn_mbcnt_lo((uint32_t)mask, 0));
        if (pred) sqq[wv][qn + below] = key;
        __builtin_amdgcn_wave_barrier();
        qn += __popcll(mask);
        if (qn >= DRAIN_AT) drain();
      }
    }
  }
  if (qn > 0) drain();

  if (lane < MARGIN) rid[wv][lane] = (int)(uint32_t)(stp[wv][lane] & 0xFFFFFFFFull);
  __syncthreads();

  const double xn = (double)xnf, yn = (double)ynf, zn = (double)znf;
  const double sqn = xn * xn + yn * yn + zn * zn;
  double myd2 = 0.0;
  int myid = 0;
  if (lane < MARGIN) {
    myid = rid[wv][lane];
    double gx = (double)sb[myid], gy = (double)sb[NPTS + myid], gz = (double)sb[2 * NPTS + myid];
    double gsq = gx * gx + gy * gy + gz * gz;
    double dot = xn * gx + yn * gy + zn * gz;
    double d2 = sqn + gsq - 2.0 * dot;
    if (d2 < 0.0) d2 = 0.0;
    myd2 = d2;
    rd2[wv][lane] = d2;
  }
  __syncthreads();
  if (lane < MARGIN) {
    int rk = 0;
    for (int m = 0; m < MARGIN; ++m) {
      double dm = rd2[wv][m];
      rk += (dm < myd2) || (dm == myd2 && rid[wv][m] < myid);
    }
    if (rk < KNN) snbr[wv][rk] = myid;
  }
  __syncthreads();

  const double txn = (double)tb[n], tyn = (double)tb[NPTS + n], tzn = (double)tb[2 * NPTS + n];
  const int p = lane;
  double loss = 0.0, reg = 0.0;
  if (p < NPAIR) {
    int g1 = snbr[wv][dCOMB_A[p]];
    int g2 = snbr[wv][dCOMB_B[p]];

    double ax = (double)sb[g1] - xn, ay = (double)sb[NPTS + g1] - yn, az = (double)sb[2 * NPTS + g1] - zn;
    double bx = (double)sb[g2] - xn, by = (double)sb[NPTS + g2] - yn, bz = (double)sb[2 * NPTS + g2] - zn;
    double cx = ay * bz - az * by;
    double cy = az * bx - ax * bz;
    double cz = ax * by - ay * bx;
    double s  = cx * cx + cy * cy + cz * cz;
    double a_s = (s > 0.0) ? 0.5 * sqrt(s) : 0.0;

    double ux = (double)tb[g1] - txn, uy = (double)tb[NPTS + g1] - tyn, uz = (double)tb[2 * NPTS + g1] - tzn;
    double vx = (double)tb[g2] - txn, vy = (double)tb[NPTS + g2] - tyn, vz = (double)tb[2 * NPTS + g2] - tzn;
    double wx = uy * vz - uz * vy;
    double wy = uz * vx - ux * vz;
    double wz = ux * vy - uy * vx;
    double t2 = wx * wx + wy * wy + wz * wz;
    double a_t = (t2 > 0.0) ? 0.5 * sqrt(t2) : 0.0;

    double ate = a_t + EPSD;
    double d   = a_s - ate;
    double numer = (EPSD * EPSD + EPSD * EPSD) + d * d;
    double denom = (EPSD + EPSD) + (a_s + ate);
    loss = numer / denom;
    reg  = sqrt(numer);
    lsA[wv][p] = loss;
  }
  __syncthreads();

  if (p < NPAIR) {
    int rk = 0;
    for (int m = 0; m < NPAIR; ++m) {
      double lm = lsA[wv][m];
      rk += (lm < loss) || (lm == loss && m < p);
    }
    lsB[wv][rk] = loss;
  }
  __syncthreads();
  double tot2 = 0.0;
  if (p < NPAIR) {
    tot2 = lsB[wv][p] + 0.1 * reg;
    lsA[wv][p] = tot2;
  }
  __syncthreads();
  if (p < NPAIR) {
    int rk = 0;
    for (int m = 0; m < NPAIR; ++m) {
      double tm = lsA[wv][m];
      rk += (tm < tot2) || (tm == tot2 && m < p);
    }
    if (rk == (NPAIR - 1) / 2) smed[wv] = tot2;
  }
  __syncthreads();
  double med = smed[wv];
  if (p < KNN) {
    double t = (tot2 > 3.0 * med) ? 0.0 : tot2;
    ssum[wv][p] = sqrt(t + EPSD);
  }
  __syncthreads();
  if (lane == 0) {
    double sum = 0.0;
#pragma unroll
    for (int q = 0; q < KNN; ++q) sum += ssum[wv][q];
    mean_out[b * NPTS + n] = (float)(sum / 10.0);
  }
}

// ---------------- finalize (unchanged) ----------------
__global__ __launch_bounds__(1024) void gfm_finalize(float* __restrict__ buf) {
  __shared__ float red[16];
  const int b = blockIdx.x;
  const int tid = threadIdx.x;
  float* __restrict__ mb = buf + b * NPTS;

  float v[8];
  float mn = 3.4e38f;
#pragma unroll
  for (int r = 0; r < 8; ++r) {
    v[r] = mb[tid + r * 1024];
    mn = fminf(mn, v[r]);
  }
#pragma unroll
  for (int s = 32; s >= 1; s >>= 1)
    mn = fminf(mn, __shfl_xor(mn, s, 64));
  if ((tid & 63) == 0) red[tid >> 6] = mn;
  __syncthreads();
  mn = red[0];
#pragma unroll
  for (int q = 1; q < 16; ++q) mn = fminf(mn, red[q]);
  __syncthreads();

#pragma unroll
  for (int r = 0; r < 8; ++r) {
    double t = (double)v[r] - (double)mn;
    double w = 2.0 / (1.0 + exp(20.0 * t));
    mb[tid + r * 1024] = (w > 0.5) ? 1.0f : 0.0f;
  }
}

extern "C" void kernel_launch(void* const* d_in, const int* in_sizes, int n_in,
                              void* d_out, int out_size, void* d_ws, size_t ws_size,
                              hipStream_t stream) {
  const float* src = (const float*)d_in[0];
  const float* tgt = (const float*)d_in[1];
  float* out = (float*)d_out;

  const size_t nP = (size_t)NBATCH * NPTS;
  const size_t sz_pts  = nP * sizeof(float4);                 // 512 KiB
  const size_t sz_oidx = nP * sizeof(uint32_t);               // 128 KiB
  const size_t sz_cs   = (size_t)NBATCH * (NCELL + 1) * 4;    // ~512 KiB
  const size_t sz_cc   = (size_t)NBATCH * NCELL * 4;          // 512 KiB
  const size_t need = sz_pts + sz_oidx + sz_cs + sz_cc;

  if (ws_size >= need) {
    char* w = (char*)d_ws;
    float4*   pts = (float4*)w;
    uint32_t* oid = (uint32_t*)(w + sz_pts);
    uint32_t* cst = (uint32_t*)(w + sz_pts + sz_oidx);
    uint32_t* ccu = (uint32_t*)(w + sz_pts + sz_oidx + sz_cs);

    zero_cells<<<(NBATCH * NCELL + 255) / 256, 256, 0, stream>>>(ccu);
    grid_count<<<(int)(nP / 256), 256, 0, stream>>>(src, ccu);
    grid_scan<<<NBATCH, 1024, 0, stream>>>(ccu, cst);
    grid_scatter<<<(int)(nP / 256), 256, 0, stream>>>(src, ccu, pts, oid);
    gfm_grid<<<NBATCH * NPTS / 4, 256, 0, stream>>>(src, tgt, pts, oid, cst, out);
  } else if (ws_size >= sz_pts) {
    float4* pk = (float4*)d_ws;
    pack_pts<<<(int)(nP / 256), 256, 0, stream>>>(src, pk);
    gfm_wave<true><<<NBATCH * NPTS / 4, 256, 0, stream>>>(src, tgt, pk, out);
  } else {
    gfm_wave<false><<<NBATCH * NPTS / 4, 256, 0, stream>>>(src, tgt, nullptr, out);
  }
  gfm_finalize<<<NBATCH, 1024, 0, stream>>>(out);
}

// Round 13
// 199.821 us; speedup vs baseline: 1.7191x; 1.7191x over previous
//
#include <hip/hip_runtime.h>
#include <cstdint>
#include <cstddef>

#define NPTS 8192
#define NBATCH 4
#define KNN 10
#define NPAIR 45
#define TILE 512
#define MARGIN 12
#define QSZ 96
#define DRAIN_AT 16
#define EPSD 1e-6
#define GRID 14
#define NCELL (GRID*GRID*GRID)
#define HCELL 0.7f
#define ORG (-4.9f)

__device__ __constant__ int dCOMB_A[NPAIR] = {
  0,0,0,0,0,0,0,0,0, 1,1,1,1,1,1,1,1, 2,2,2,2,2,2,2,
  3,3,3,3,3,3, 4,4,4,4,4, 5,5,5,5, 6,6,6, 7,7, 8};
__device__ __constant__ int dCOMB_B[NPAIR] = {
  1,2,3,4,5,6,7,8,9, 2,3,4,5,6,7,8,9, 3,4,5,6,7,8,9,
  4,5,6,7,8,9, 5,6,7,8,9, 6,7,8,9, 7,8,9, 8,9, 9};

__device__ __forceinline__ void cell_coords(float x, float y, float z,
                                            int& cx, int& cy, int& cz) {
  cx = (int)floorf((x - ORG) * (1.0f / HCELL));
  cy = (int)floorf((y - ORG) * (1.0f / HCELL));
  cz = (int)floorf((z - ORG) * (1.0f / HCELL));
  cx = min(max(cx, 0), GRID - 1);
  cy = min(max(cy, 0), GRID - 1);
  cz = min(max(cz, 0), GRID - 1);
}

// ---------------- grid build ----------------
__global__ __launch_bounds__(256) void zero_cells(uint32_t* ccur) {
  int i = blockIdx.x * 256 + threadIdx.x;
  if (i < NBATCH * NCELL) ccur[i] = 0;
}

__global__ __launch_bounds__(256) void grid_count(const float* __restrict__ src,
                                                  uint32_t* ccur) {
  int i = blockIdx.x * 256 + threadIdx.x;          // 0..32767
  int b = i >> 13, p = i & (NPTS - 1);
  const float* sb = src + (size_t)b * 3 * NPTS;
  int cx, cy, cz;
  cell_coords(sb[p], sb[NPTS + p], sb[2 * NPTS + p], cx, cy, cz);
  atomicAdd(&ccur[b * NCELL + ((cz * GRID) + cy) * GRID + cx], 1u);
}

// One block/batch, single chunk: 1024 thr x 4 cells. Exclusive scan -> cstart + cursors.
__global__ __launch_bounds__(1024) void grid_scan(uint32_t* ccur,
                                                  uint32_t* __restrict__ cstart) {
  __shared__ uint32_t swv[16];
  const int b = blockIdx.x;
  const int tid = threadIdx.x, lane = tid & 63, wid = tid >> 6;
  const uint32_t base = b * NCELL;
  const int i0 = tid * 4;
  uint32_t v[4], ts = 0;
#pragma unroll
  for (int k = 0; k < 4; ++k) {
    v[k] = (i0 + k < NCELL) ? ccur[base + i0 + k] : 0u;
    ts += v[k];
  }
  uint32_t x = ts;
#pragma unroll
  for (int off = 1; off < 64; off <<= 1) {
    uint32_t y = __shfl_up(x, off, 64);
    if (lane >= off) x += y;
  }
  if (lane == 63) swv[wid] = x;
  __syncthreads();
  uint32_t wpre = 0, bsum = 0;
  for (int w = 0; w < 16; ++w) { uint32_t s = swv[w]; bsum += s; if (w < wid) wpre += s; }
  uint32_t excl = wpre + (x - ts);
#pragma unroll
  for (int k = 0; k < 4; ++k) {
    if (i0 + k < NCELL) {
      cstart[b * (NCELL + 1) + i0 + k] = excl;
      ccur[base + i0 + k] = excl;
      excl += v[k];
    }
  }
  if (tid == 0) cstart[b * (NCELL + 1) + NCELL] = bsum;   // = NPTS
}

__global__ __launch_bounds__(256) void grid_scatter(const float* __restrict__ src,
                                                    uint32_t* ccur,
                                                    float4* __restrict__ pts,
                                                    uint32_t* __restrict__ oidx) {
  int i = blockIdx.x * 256 + threadIdx.x;
  int b = i >> 13, p = i & (NPTS - 1);
  const float* sb = src + (size_t)b * 3 * NPTS;
  float x = sb[p], y = sb[NPTS + p], z = sb[2 * NPTS + p];
  int cx, cy, cz;
  cell_coords(x, y, z, cx, cy, cz);
  uint32_t pos = atomicAdd(&ccur[b * NCELL + ((cz * GRID) + cy) * GRID + cx], 1u);
  pts[(b << 13) + pos]  = make_float4(x, y, z, x * x + y * y + z * z);
  oidx[(b << 13) + pos] = (uint32_t)p;
}

// ---------------- main: row-contiguous box walk ----------------
__global__ __launch_bounds__(256) void gfm_grid(const float* __restrict__ src,
                                                const float* __restrict__ tgt,
                                                const float4* __restrict__ pts,
                                                const uint32_t* __restrict__ oidx,
                                                const uint32_t* __restrict__ cstart,
                                                float* __restrict__ mean_out) {
  __shared__ uint64_t sqq[4][QSZ];
  __shared__ uint64_t stp[4][MARGIN];
  __shared__ double lsA[4][NPAIR];
  __shared__ double lsB[4][NPAIR];
  __shared__ double smed[4];
  __shared__ double ssum[4][KNN];
  __shared__ double rd2[4][MARGIN];
  __shared__ int    rid[4][MARGIN];
  __shared__ int    snbr[4][KNN];

  const int tid  = threadIdx.x;
  const int wv   = tid >> 6;
  const int lane = tid & 63;
  const int b    = blockIdx.x >> 11;
  const int n    = ((blockIdx.x & 2047) << 2) | wv;

  const float* __restrict__ sb = src + (size_t)b * 3 * NPTS;
  const float* __restrict__ tb = tgt + (size_t)b * 3 * NPTS;
  const float4* __restrict__ ppts = pts + ((size_t)b << 13);
  const uint32_t* __restrict__ poid = oidx + ((size_t)b << 13);
  const uint32_t* __restrict__ cs = cstart + (size_t)b * (NCELL + 1);

  const float xnf = sb[n], ynf = sb[NPTS + n], znf = sb[2 * NPTS + n];
  const float sqnf = xnf * xnf + ynf * ynf + znf * znf;

  int qcx, qcy, qcz;
  cell_coords(xnf, ynf, znf, qcx, qcy, qcz);
  float lox = ORG + qcx * HCELL, loy = ORG + qcy * HCELL, loz = ORG + qcz * HCELL;
  float dqx = fmaxf(fmaxf(lox - xnf, xnf - (lox + HCELL)), 0.0f);
  float dqy = fmaxf(fmaxf(loy - ynf, ynf - (loy + HCELL)), 0.0f);
  float dqz = fmaxf(fmaxf(loz - znf, znf - (loz + HCELL)), 0.0f);
  const float deltaq = sqrtf(dqx * dqx + dqy * dqy + dqz * dqz);

  if (lane < MARGIN) stp[wv][lane] = ~0ull;
  __builtin_amdgcn_wave_barrier();
  float tau_f = __builtin_inff();
  int qn = 0;

  auto drain = [&]() {
    if (lane < MARGIN) sqq[wv][qn + lane] = stp[wv][lane];
    __builtin_amdgcn_wave_barrier();
    const int tot = qn + MARGIN;
    uint64_t k0 = (lane < tot) ? sqq[wv][lane] : ~0ull;
    uint64_t k1 = (lane + 64 < tot) ? sqq[wv][lane + 64] : ~0ull;
    int r0 = 0, r1 = 0;
    for (int m = 0; m < tot; ++m) {
      uint64_t km = sqq[wv][m];
      r0 += (km < k0);
      r1 += (km < k1);
    }
    __builtin_amdgcn_wave_barrier();
    if (lane < tot && r0 < MARGIN) stp[wv][r0] = k0;
    if (lane + 64 < tot && r1 < MARGIN) stp[wv][r1] = k1;
    __builtin_amdgcn_wave_barrier();
    tau_f = __uint_as_float((uint32_t)(stp[wv][MARGIN - 1] >> 32));
    qn = 0;
  };

  // stream one contiguous row of cells [cx0..cx1] at (cy,cz)
  auto scan_range = [&](int cy, int cz, int cx0, int cx1) {
    if (cy < 0 || cy >= GRID || cz < 0 || cz >= GRID) return;
    cx0 = max(cx0, 0); cx1 = min(cx1, GRID - 1);
    if (cx0 > cx1) return;
    uint32_t c0 = (uint32_t)(((cz * GRID) + cy) * GRID + cx0);
    uint32_t st = cs[c0];
    uint32_t en = cs[c0 + (uint32_t)(cx1 - cx0) + 1];
    for (uint32_t base = st; base < en; base += 64) {
      uint32_t pos = base + (uint32_t)lane;
      bool act = pos < en;
      float d2 = 0.0f;
      bool pred = false;
      if (act) {
        float4 c4 = ppts[pos];
        float dot = fmaf(xnf, c4.x, fmaf(ynf, c4.y, znf * c4.z));
        d2 = fmaxf(fmaf(-2.0f, dot, sqnf + c4.w), 0.0f);
        pred = d2 <= tau_f;
      }
      uint64_t m2 = __ballot(pred);
      if (m2) {
        int below = __builtin_amdgcn_mbcnt_hi((uint32_t)(m2 >> 32),
                     __builtin_amdgcn_mbcnt_lo((uint32_t)m2, 0));
        if (pred) {
          uint64_t key = ((uint64_t)__float_as_uint(d2) << 32) | (uint64_t)poid[pos];
          sqq[wv][qn + below] = key;
        }
        __builtin_amdgcn_wave_barrier();
        qn += __popcll(m2);
        if (qn >= DRAIN_AT) drain();
      }
    }
  };

  // box r=1 (27 cells = 9 rows)
#pragma unroll
  for (int dz = -1; dz <= 1; ++dz)
#pragma unroll
    for (int dy = -1; dy <= 1; ++dy)
      scan_range(qcy + dy, qcz + dz, qcx - 1, qcx + 1);

  // shells r>=2 (rare): full rows where max(|dy|,|dz|)==r, else 2 edge cells
  for (int r = 2; r < GRID; ++r) {
    float mrg = (float)(r - 1) * HCELL - deltaq;
    if (mrg > 0.0f && mrg * mrg > tau_f * 1.0001f) break;
    for (int dz = -r; dz <= r; ++dz)
      for (int dy = -r; dy <= r; ++dy) {
        if (abs(dz) == r || abs(dy) == r) {
          scan_range(qcy + dy, qcz + dz, qcx - r, qcx + r);
        } else {
          scan_range(qcy + dy, qcz + dz, qcx - r, qcx - r);
          scan_range(qcy + dy, qcz + dz, qcx + r, qcx + r);
        }
      }
  }
  if (qn > 0) drain();

  if (lane < MARGIN) rid[wv][lane] = (int)(uint32_t)(stp[wv][lane] & 0xFFFFFFFFull);
  __syncthreads();

  // ---- exact f64 re-rank of 12 candidates (identical to R11/R12) ----
  const double xn = (double)xnf, yn = (double)ynf, zn = (double)znf;
  const double sqn = xn * xn + yn * yn + zn * zn;
  double myd2 = 0.0;
  int myid = 0;
  if (lane < MARGIN) {
    myid = rid[wv][lane];
    double gx = (double)sb[myid], gy = (double)sb[NPTS + myid], gz = (double)sb[2 * NPTS + myid];
    double gsq = gx * gx + gy * gy + gz * gz;
    double dot = xn * gx + yn * gy + zn * gz;
    double d2 = sqn + gsq - 2.0 * dot;
    if (d2 < 0.0) d2 = 0.0;
    myd2 = d2;
    rd2[wv][lane] = d2;
  }
  __syncthreads();
  if (lane < MARGIN) {
    int rk = 0;
    for (int m = 0; m < MARGIN; ++m) {
      double dm = rd2[wv][m];
      rk += (dm < myd2) || (dm == myd2 && rid[wv][m] < myid);
    }
    if (rk < KNN) snbr[wv][rk] = myid;
  }
  __syncthreads();

  // ---- phase 2 (identical to rounds 8-12) ----
  const double txn = (double)tb[n], tyn = (double)tb[NPTS + n], tzn = (double)tb[2 * NPTS + n];
  const int p = lane;
  double loss = 0.0, reg = 0.0;
  if (p < NPAIR) {
    int g1 = snbr[wv][dCOMB_A[p]];
    int g2 = snbr[wv][dCOMB_B[p]];

    double ax = (double)sb[g1] - xn, ay = (double)sb[NPTS + g1] - yn, az = (double)sb[2 * NPTS + g1] - zn;
    double bx = (double)sb[g2] - xn, by = (double)sb[NPTS + g2] - yn, bz = (double)sb[2 * NPTS + g2] - zn;
    double cx = ay * bz - az * by;
    double cy = az * bx - ax * bz;
    double cz = ax * by - ay * bx;
    double s  = cx * cx + cy * cy + cz * cz;
    double a_s = (s > 0.0) ? 0.5 * sqrt(s) : 0.0;

    double ux = (double)tb[g1] - txn, uy = (double)tb[NPTS + g1] - tyn, uz = (double)tb[2 * NPTS + g1] - tzn;
    double vx = (double)tb[g2] - txn, vy = (double)tb[NPTS + g2] - tyn, vz = (double)tb[2 * NPTS + g2] - tzn;
    double wx = uy * vz - uz * vy;
    double wy = uz * vx - ux * vz;
    double wz = ux * vy - uy * vx;
    double t2 = wx * wx + wy * wy + wz * wz;
    double a_t = (t2 > 0.0) ? 0.5 * sqrt(t2) : 0.0;

    double ate = a_t + EPSD;
    double d   = a_s - ate;
    double numer = (EPSD * EPSD + EPSD * EPSD) + d * d;
    double denom = (EPSD + EPSD) + (a_s + ate);
    loss = numer / denom;
    reg  = sqrt(numer);
    lsA[wv][p] = loss;
  }
  __syncthreads();

  if (p < NPAIR) {
    int rk = 0;
    for (int m = 0; m < NPAIR; ++m) {
      double lm = lsA[wv][m];
      rk += (lm < loss) || (lm == loss && m < p);
    }
    lsB[wv][rk] = loss;
  }
  __syncthreads();
  double tot2 = 0.0;
  if (p < NPAIR) {
    tot2 = lsB[wv][p] + 0.1 * reg;
    lsA[wv][p] = tot2;
  }
  __syncthreads();
  if (p < NPAIR) {
    int rk = 0;
    for (int m = 0; m < NPAIR; ++m) {
      double tm = lsA[wv][m];
      rk += (tm < tot2) || (tm == tot2 && m < p);
    }
    if (rk == (NPAIR - 1) / 2) smed[wv] = tot2;
  }
  __syncthreads();
  double med = smed[wv];
  if (p < KNN) {
    double t = (tot2 > 3.0 * med) ? 0.0 : tot2;
    ssum[wv][p] = sqrt(t + EPSD);
  }
  __syncthreads();
  if (lane == 0) {
    double sum = 0.0;
#pragma unroll
    for (int q = 0; q < KNN; ++q) sum += ssum[wv][q];
    mean_out[b * NPTS + n] = (float)(sum / 10.0);
  }
}

// ---------------- fallback: R11 full-scan kernels ----------------
__global__ __launch_bounds__(256) void pack_pts(const float* __restrict__ src,
                                                float4* __restrict__ pk) {
  int i = blockIdx.x * 256 + threadIdx.x;
  int b = i >> 13, p = i & (NPTS - 1);
  const float* sb = src + (size_t)b * 3 * NPTS;
  float x = sb[p], y = sb[NPTS + p], z = sb[2 * NPTS + p];
  pk[i] = make_float4(x, y, z, x * x + y * y + z * z);
}

template <bool PACKED>
__global__ __launch_bounds__(256) void gfm_wave(const float* __restrict__ src,
                                                const float* __restrict__ tgt,
                                                const float4* __restrict__ pk,
                                                float* __restrict__ mean_out) {
  __shared__ float4   s4[TILE];
  __shared__ uint64_t sqq[4][QSZ];
  __shared__ uint64_t stp[4][MARGIN];
  __shared__ double lsA[4][NPAIR];
  __shared__ double lsB[4][NPAIR];
  __shared__ double smed[4];
  __shared__ double ssum[4][KNN];
  __shared__ double rd2[4][MARGIN];
  __shared__ int    rid[4][MARGIN];
  __shared__ int    snbr[4][KNN];

  const int tid  = threadIdx.x;
  const int wv   = tid >> 6;
  const int lane = tid & 63;
  const int b    = blockIdx.x >> 11;
  const int n    = ((blockIdx.x & 2047) << 2) | wv;

  const float* __restrict__ sb = src + (size_t)b * 3 * NPTS;
  const float* __restrict__ tb = tgt + (size_t)b * 3 * NPTS;

  const float xnf = sb[n], ynf = sb[NPTS + n], znf = sb[2 * NPTS + n];
  const float sqnf = xnf * xnf + ynf * ynf + znf * znf;

  if (lane < MARGIN) stp[wv][lane] = ~0ull;
  __builtin_amdgcn_wave_barrier();
  float tau_f = __builtin_inff();
  int qn = 0;

  auto drain = [&]() {
    if (lane < MARGIN) sqq[wv][qn + lane] = stp[wv][lane];
    __builtin_amdgcn_wave_barrier();
    const int tot = qn + MARGIN;
    uint64_t k0 = (lane < tot) ? sqq[wv][lane] : ~0ull;
    uint64_t k1 = (lane + 64 < tot) ? sqq[wv][lane + 64] : ~0ull;
    int r0 = 0, r1 = 0;
    for (int m = 0; m < tot; ++m) {
      uint64_t km = sqq[wv][m];
      r0 += (km < k0);
      r1 += (km < k1);
    }
    __builtin_amdgcn_wave_barrier();
    if (lane < tot && r0 < MARGIN) stp[wv][r0] = k0;
    if (lane + 64 < tot && r1 < MARGIN) stp[wv][r1] = k1;
    __builtin_amdgcn_wave_barrier();
    tau_f = __uint_as_float((uint32_t)(stp[wv][MARGIN - 1] >> 32));
    qn = 0;
  };

  for (int t0 = 0; t0 < NPTS; t0 += TILE) {
    __syncthreads();
    if (PACKED) {
      const float4* __restrict__ g = pk + (size_t)b * NPTS + t0;
#pragma unroll
      for (int r = 0; r < TILE / 256; ++r) {
        int i = tid + r * 256;
        s4[i] = g[i];
      }
    } else {
#pragma unroll
      for (int r = 0; r < TILE / 256; ++r) {
        int i = tid + r * 256;
        float x = sb[t0 + i], y = sb[NPTS + t0 + i], z = sb[2 * NPTS + t0 + i];
        s4[i] = make_float4(x, y, z, x * x + y * y + z * z);
      }
    }
    __syncthreads();
#pragma unroll 2
    for (int r = 0; r < TILE / 64; ++r) {
      int j = lane + (r << 6);
      float4 c = s4[j];
      float dot = fmaf(xnf, c.x, fmaf(ynf, c.y, znf * c.z));
      float d2 = fmaxf(fmaf(-2.0f, dot, sqnf + c.w), 0.0f);
      bool pred = d2 <= tau_f;
      uint64_t mask = __ballot(pred);
      if (mask) {
        uint64_t key = ((uint64_t)__float_as_uint(d2) << 32) | (uint32_t)(t0 + j);
        int below = __builtin_amdgcn_mbcnt_hi((uint32_t)(mask >> 32),
                     __builtin_amdgcn_mbcnt_lo((uint32_t)mask, 0));
        if (pred) sqq[wv][qn + below] = key;
        __builtin_amdgcn_wave_barrier();
        qn += __popcll(mask);
        if (qn >= DRAIN_AT) drain();
      }
    }
  }
  if (qn > 0) drain();

  if (lane < MARGIN) rid[wv][lane] = (int)(uint32_t)(stp[wv][lane] & 0xFFFFFFFFull);
  __syncthreads();

  const double xn = (double)xnf, yn = (double)ynf, zn = (double)znf;
  const double sqn = xn * xn + yn * yn + zn * zn;
  double myd2 = 0.0;
  int myid = 0;
  if (lane < MARGIN) {
    myid = rid[wv][lane];
    double gx = (double)sb[myid], gy = (double)sb[NPTS + myid], gz = (double)sb[2 * NPTS + myid];
    double gsq = gx * gx + gy * gy + gz * gz;
    double dot = xn * gx + yn * gy + zn * gz;
    double d2 = sqn + gsq - 2.0 * dot;
    if (d2 < 0.0) d2 = 0.0;
    myd2 = d2;
    rd2[wv][lane] = d2;
  }
  __syncthreads();
  if (lane < MARGIN) {
    int rk = 0;
    for (int m = 0; m < MARGIN; ++m) {
      double dm = rd2[wv][m];
      rk += (dm < myd2) || (dm == myd2 && rid[wv][m] < myid);
    }
    if (rk < KNN) snbr[wv][rk] = myid;
  }
  __syncthreads();

  const double txn = (double)tb[n], tyn = (double)tb[NPTS + n], tzn = (double)tb[2 * NPTS + n];
  const int p = lane;
  double loss = 0.0, reg = 0.0;
  if (p < NPAIR) {
    int g1 = snbr[wv][dCOMB_A[p]];
    int g2 = snbr[wv][dCOMB_B[p]];

    double ax = (double)sb[g1] - xn, ay = (double)sb[NPTS + g1] - yn, az = (double)sb[2 * NPTS + g1] - zn;
    double bx = (double)sb[g2] - xn, by = (double)sb[NPTS + g2] - yn, bz = (double)sb[2 * NPTS + g2] - zn;
    double cx = ay * bz - az * by;
    double cy = az * bx - ax * bz;
    double cz = ax * by - ay * bx;
    double s  = cx * cx + cy * cy + cz * cz;
    double a_s = (s > 0.0) ? 0.5 * sqrt(s) : 0.0;

    double ux = (double)tb[g1] - txn, uy = (double)tb[NPTS + g1] - tyn, uz = (double)tb[2 * NPTS + g1] - tzn;
    double vx = (double)tb[g2] - txn, vy = (double)tb[NPTS + g2] - tyn, vz = (double)tb[2 * NPTS + g2] - tzn;
    double wx = uy * vz - uz * vy;
    double wy = uz * vx - ux * vz;
    double wz = ux * vy - uy * vx;
    double t2 = wx * wx + wy * wy + wz * wz;
    double a_t = (t2 > 0.0) ? 0.5 * sqrt(t2) : 0.0;

    double ate = a_t + EPSD;
    double d   = a_s - ate;
    double numer = (EPSD * EPSD + EPSD * EPSD) + d * d;
    double denom = (EPSD + EPSD) + (a_s + ate);
    loss = numer / denom;
    reg  = sqrt(numer);
    lsA[wv][p] = loss;
  }
  __syncthreads();

  if (p < NPAIR) {
    int rk = 0;
    for (int m = 0; m < NPAIR; ++m) {
      double lm = lsA[wv][m];
      rk += (lm < loss) || (lm == loss && m < p);
    }
    lsB[wv][rk] = loss;
  }
  __syncthreads();
  double tot2 = 0.0;
  if (p < NPAIR) {
    tot2 = lsB[wv][p] + 0.1 * reg;
    lsA[wv][p] = tot2;
  }
  __syncthreads();
  if (p < NPAIR) {
    int rk = 0;
    for (int m = 0; m < NPAIR; ++m) {
      double tm = lsA[wv][m];
      rk += (tm < tot2) || (tm == tot2 && m < p);
    }
    if (rk == (NPAIR - 1) / 2) smed[wv] = tot2;
  }
  __syncthreads();
  double med = smed[wv];
  if (p < KNN) {
    double t = (tot2 > 3.0 * med) ? 0.0 : tot2;
    ssum[wv][p] = sqrt(t + EPSD);
  }
  __syncthreads();
  if (lane == 0) {
    double sum = 0.0;
#pragma unroll
    for (int q = 0; q < KNN; ++q) sum += ssum[wv][q];
    mean_out[b * NPTS + n] = (float)(sum / 10.0);
  }
}

// ---------------- finalize (unchanged) ----------------
__global__ __launch_bounds__(1024) void gfm_finalize(float* __restrict__ buf) {
  __shared__ float red[16];
  const int b = blockIdx.x;
  const int tid = threadIdx.x;
  float* __restrict__ mb = buf + b * NPTS;

  float v[8];
  float mn = 3.4e38f;
#pragma unroll
  for (int r = 0; r < 8; ++r) {
    v[r] = mb[tid + r * 1024];
    mn = fminf(mn, v[r]);
  }
#pragma unroll
  for (int s = 32; s >= 1; s >>= 1)
    mn = fminf(mn, __shfl_xor(mn, s, 64));
  if ((tid & 63) == 0) red[tid >> 6] = mn;
  __syncthreads();
  mn = red[0];
#pragma unroll
  for (int q = 1; q < 16; ++q) mn = fminf(mn, red[q]);
  __syncthreads();

#pragma unroll
  for (int r = 0; r < 8; ++r) {
    double t = (double)v[r] - (double)mn;
    double w = 2.0 / (1.0 + exp(20.0 * t));
    mb[tid + r * 1024] = (w > 0.5) ? 1.0f : 0.0f;
  }
}

extern "C" void kernel_launch(void* const* d_in, const int* in_sizes, int n_in,
                              void* d_out, int out_size, void* d_ws, size_t ws_size,
                              hipStream_t stream) {
  const float* src = (const float*)d_in[0];
  const float* tgt = (const float*)d_in[1];
  float* out = (float*)d_out;

  const size_t nP = (size_t)NBATCH * NPTS;
  const size_t sz_pts  = nP * sizeof(float4);                 // 512 KiB
  const size_t sz_oidx = nP * sizeof(uint32_t);               // 128 KiB
  const size_t sz_cs   = (size_t)NBATCH * (NCELL + 1) * 4;    // ~43 KiB
  const size_t sz_cc   = (size_t)NBATCH * NCELL * 4;          // ~43 KiB
  const size_t need = sz_pts + sz_oidx + sz_cs + sz_cc;

  if (ws_size >= need) {
    char* w = (char*)d_ws;
    float4*   pts = (float4*)w;
    uint32_t* oid = (uint32_t*)(w + sz_pts);
    uint32_t* cst = (uint32_t*)(w + sz_pts + sz_oidx);
    uint32_t* ccu = (uint32_t*)(w + sz_pts + sz_oidx + sz_cs);

    zero_cells<<<(NBATCH * NCELL + 255) / 256, 256, 0, stream>>>(ccu);
    grid_count<<<(int)(nP / 256), 256, 0, stream>>>(src, ccu);
    grid_scan<<<NBATCH, 1024, 0, stream>>>(ccu, cst);
    grid_scatter<<<(int)(nP / 256), 256, 0, stream>>>(src, ccu, pts, oid);
    gfm_grid<<<NBATCH * NPTS / 4, 256, 0, stream>>>(src, tgt, pts, oid, cst, out);
  } else if (ws_size >= sz_pts) {
    float4* pk = (float4*)d_ws;
    pack_pts<<<(int)(nP / 256), 256, 0, stream>>>(src, pk);
    gfm_wave<true><<<NBATCH * NPTS / 4, 256, 0, stream>>>(src, tgt, pk, out);
  } else {
    gfm_wave<false><<<NBATCH * NPTS / 4, 256, 0, stream>>>(src, tgt, nullptr, out);
  }
  gfm_finalize<<<NBATCH, 1024, 0, stream>>>(out);
}

// Round 14
// 154.524 us; speedup vs baseline: 2.2230x; 1.2931x over previous
//
#include <hip/hip_runtime.h>
#include <cstdint>
#include <cstddef>

#define NPTS 8192
#define NBATCH 4
#define KNN 10
#define NPAIR 45
#define TILE 512
#define MARGIN 12
#define QSZ 96
#define DRAIN_AT 16
#define EPSD 1e-6
#define GRID 14
#define NCELL (GRID*GRID*GRID)
#define HCELL 0.7f
#define ORG (-4.9f)

__device__ __constant__ int dCOMB_A[NPAIR] = {
  0,0,0,0,0,0,0,0,0, 1,1,1,1,1,1,1,1, 2,2,2,2,2,2,2,
  3,3,3,3,3,3, 4,4,4,4,4, 5,5,5,5, 6,6,6, 7,7, 8};
__device__ __constant__ int dCOMB_B[NPAIR] = {
  1,2,3,4,5,6,7,8,9, 2,3,4,5,6,7,8,9, 3,4,5,6,7,8,9,
  4,5,6,7,8,9, 5,6,7,8,9, 6,7,8,9, 7,8,9, 8,9, 9};

__device__ __forceinline__ void cell_coords(float x, float y, float z,
                                            int& cx, int& cy, int& cz) {
  cx = (int)floorf((x - ORG) * (1.0f / HCELL));
  cy = (int)floorf((y - ORG) * (1.0f / HCELL));
  cz = (int)floorf((z - ORG) * (1.0f / HCELL));
  cx = min(max(cx, 0), GRID - 1);
  cy = min(max(cy, 0), GRID - 1);
  cz = min(max(cz, 0), GRID - 1);
}

// ---------------- grid build ----------------
__global__ __launch_bounds__(256) void zero_cells(uint32_t* ccur) {
  int i = blockIdx.x * 256 + threadIdx.x;
  if (i < NBATCH * NCELL) ccur[i] = 0;
}

__global__ __launch_bounds__(256) void grid_count(const float* __restrict__ src,
                                                  uint32_t* ccur) {
  int i = blockIdx.x * 256 + threadIdx.x;          // 0..32767
  int b = i >> 13, p = i & (NPTS - 1);
  const float* sb = src + (size_t)b * 3 * NPTS;
  int cx, cy, cz;
  cell_coords(sb[p], sb[NPTS + p], sb[2 * NPTS + p], cx, cy, cz);
  atomicAdd(&ccur[b * NCELL + ((cz * GRID) + cy) * GRID + cx], 1u);
}

// One block/batch, single chunk: 1024 thr x 4 cells. Exclusive scan -> cstart + cursors.
__global__ __launch_bounds__(1024) void grid_scan(uint32_t* ccur,
                                                  uint32_t* __restrict__ cstart) {
  __shared__ uint32_t swv[16];
  const int b = blockIdx.x;
  const int tid = threadIdx.x, lane = tid & 63, wid = tid >> 6;
  const uint32_t base = b * NCELL;
  const int i0 = tid * 4;
  uint32_t v[4], ts = 0;
#pragma unroll
  for (int k = 0; k < 4; ++k) {
    v[k] = (i0 + k < NCELL) ? ccur[base + i0 + k] : 0u;
    ts += v[k];
  }
  uint32_t x = ts;
#pragma unroll
  for (int off = 1; off < 64; off <<= 1) {
    uint32_t y = __shfl_up(x, off, 64);
    if (lane >= off) x += y;
  }
  if (lane == 63) swv[wid] = x;
  __syncthreads();
  uint32_t wpre = 0, bsum = 0;
  for (int w = 0; w < 16; ++w) { uint32_t s = swv[w]; bsum += s; if (w < wid) wpre += s; }
  uint32_t excl = wpre + (x - ts);
#pragma unroll
  for (int k = 0; k < 4; ++k) {
    if (i0 + k < NCELL) {
      cstart[b * (NCELL + 1) + i0 + k] = excl;
      ccur[base + i0 + k] = excl;
      excl += v[k];
    }
  }
  if (tid == 0) cstart[b * (NCELL + 1) + NCELL] = bsum;   // = NPTS
}

__global__ __launch_bounds__(256) void grid_scatter(const float* __restrict__ src,
                                                    uint32_t* ccur,
                                                    float4* __restrict__ pts,
                                                    uint32_t* __restrict__ oidx) {
  int i = blockIdx.x * 256 + threadIdx.x;
  int b = i >> 13, p = i & (NPTS - 1);
  const float* sb = src + (size_t)b * 3 * NPTS;
  float x = sb[p], y = sb[NPTS + p], z = sb[2 * NPTS + p];
  int cx, cy, cz;
  cell_coords(x, y, z, cx, cy, cz);
  uint32_t pos = atomicAdd(&ccur[b * NCELL + ((cz * GRID) + cy) * GRID + cx], 1u);
  pts[(b << 13) + pos]  = make_float4(x, y, z, x * x + y * y + z * z);
  oidx[(b << 13) + pos] = (uint32_t)p;
}

// ---------------- main: row-contiguous box walk, center-first + row pruning ----------------
__global__ __launch_bounds__(256) void gfm_grid(const float* __restrict__ src,
                                                const float* __restrict__ tgt,
                                                const float4* __restrict__ pts,
                                                const uint32_t* __restrict__ oidx,
                                                const uint32_t* __restrict__ cstart,
                                                float* __restrict__ mean_out) {
  __shared__ uint64_t sqq[4][QSZ];
  __shared__ uint64_t stp[4][MARGIN];
  __shared__ double lsA[4][NPAIR];
  __shared__ double lsB[4][NPAIR];
  __shared__ double smed[4];
  __shared__ double ssum[4][KNN];
  __shared__ double rd2[4][MARGIN];
  __shared__ int    rid[4][MARGIN];
  __shared__ int    snbr[4][KNN];

  const int tid  = threadIdx.x;
  const int wv   = tid >> 6;
  const int lane = tid & 63;
  const int b    = blockIdx.x >> 11;
  const int n    = ((blockIdx.x & 2047) << 2) | wv;

  const float* __restrict__ sb = src + (size_t)b * 3 * NPTS;
  const float* __restrict__ tb = tgt + (size_t)b * 3 * NPTS;
  const float4* __restrict__ ppts = pts + ((size_t)b << 13);
  const uint32_t* __restrict__ poid = oidx + ((size_t)b << 13);
  const uint32_t* __restrict__ cs = cstart + (size_t)b * (NCELL + 1);

  const float xnf = sb[n], ynf = sb[NPTS + n], znf = sb[2 * NPTS + n];
  const float sqnf = xnf * xnf + ynf * ynf + znf * znf;

  int qcx, qcy, qcz;
  cell_coords(xnf, ynf, znf, qcx, qcy, qcz);
  float lox = ORG + qcx * HCELL, loy = ORG + qcy * HCELL, loz = ORG + qcz * HCELL;
  float dqx = fmaxf(fmaxf(lox - xnf, xnf - (lox + HCELL)), 0.0f);
  float dqy = fmaxf(fmaxf(loy - ynf, ynf - (loy + HCELL)), 0.0f);
  float dqz = fmaxf(fmaxf(loz - znf, znf - (loz + HCELL)), 0.0f);
  const float deltaq = sqrtf(dqx * dqx + dqy * dqy + dqz * dqz);

  if (lane < MARGIN) stp[wv][lane] = ~0ull;
  __builtin_amdgcn_wave_barrier();
  float tau_f = __builtin_inff();
  int qn = 0;

  auto drain = [&]() {
    if (lane < MARGIN) sqq[wv][qn + lane] = stp[wv][lane];
    __builtin_amdgcn_wave_barrier();
    const int tot = qn + MARGIN;
    uint64_t k0 = (lane < tot) ? sqq[wv][lane] : ~0ull;
    uint64_t k1 = (lane + 64 < tot) ? sqq[wv][lane + 64] : ~0ull;
    int r0 = 0, r1 = 0;
    for (int m = 0; m < tot; ++m) {
      uint64_t km = sqq[wv][m];
      r0 += (km < k0);
      r1 += (km < k1);
    }
    __builtin_amdgcn_wave_barrier();
    if (lane < tot && r0 < MARGIN) stp[wv][r0] = k0;
    if (lane + 64 < tot && r1 < MARGIN) stp[wv][r1] = k1;
    __builtin_amdgcn_wave_barrier();
    tau_f = __uint_as_float((uint32_t)(stp[wv][MARGIN - 1] >> 32));
    qn = 0;
  };

  // stream one contiguous row of cells [cx0..cx1] at (cy,cz), with exact
  // conservative min-d2 pruning against current tau
  auto scan_range = [&](int cy, int cz, int cx0, int cx1) {
    if (cy < 0 || cy >= GRID || cz < 0 || cz >= GRID) return;
    cx0 = max(cx0, 0); cx1 = min(cx1, GRID - 1);
    if (cx0 > cx1) return;
    float bx0 = ORG + cx0 * HCELL, bx1 = ORG + (cx1 + 1) * HCELL;
    float by0 = ORG + cy * HCELL,  by1 = by0 + HCELL;
    float bz0 = ORG + cz * HCELL,  bz1 = bz0 + HCELL;
    float ddx = fmaxf(fmaxf(bx0 - xnf, xnf - bx1), 0.0f);
    float ddy = fmaxf(fmaxf(by0 - ynf, ynf - by1), 0.0f);
    float ddz = fmaxf(fmaxf(bz0 - znf, znf - bz1), 0.0f);
    float rowmin = ddx * ddx + ddy * ddy + ddz * ddz;
    if (rowmin > tau_f * 1.001f + 1e-5f) return;   // provably all-beyond-tau
    uint32_t c0 = (uint32_t)(((cz * GRID) + cy) * GRID + cx0);
    uint32_t st = cs[c0];
    uint32_t en = cs[c0 + (uint32_t)(cx1 - cx0) + 1];
    for (uint32_t base = st; base < en; base += 64) {
      uint32_t pos = base + (uint32_t)lane;
      bool act = pos < en;
      float d2 = 0.0f;
      bool pred = false;
      if (act) {
        float4 c4 = ppts[pos];
        float dot = fmaf(xnf, c4.x, fmaf(ynf, c4.y, znf * c4.z));
        d2 = fmaxf(fmaf(-2.0f, dot, sqnf + c4.w), 0.0f);
        pred = d2 <= tau_f;
      }
      uint64_t m2 = __ballot(pred);
      if (m2) {
        int below = __builtin_amdgcn_mbcnt_hi((uint32_t)(m2 >> 32),
                     __builtin_amdgcn_mbcnt_lo((uint32_t)m2, 0));
        if (pred) {
          uint64_t key = ((uint64_t)__float_as_uint(d2) << 32) | (uint64_t)poid[pos];
          sqq[wv][qn + below] = key;
        }
        __builtin_amdgcn_wave_barrier();
        qn += __popcll(m2);
        if (qn >= DRAIN_AT) drain();
      }
    }
  };

  // center row FIRST (tightens tau immediately), then remaining 8 box-1 rows
  scan_range(qcy, qcz, qcx - 1, qcx + 1);
#pragma unroll
  for (int dz = -1; dz <= 1; ++dz)
#pragma unroll
    for (int dy = -1; dy <= 1; ++dy)
      if (!(dy == 0 && dz == 0))
        scan_range(qcy + dy, qcz + dz, qcx - 1, qcx + 1);

  // shells r>=2 (rare): full rows where max(|dy|,|dz|)==r, else 2 edge cells
  for (int r = 2; r < GRID; ++r) {
    float mrg = (float)(r - 1) * HCELL - deltaq;
    if (mrg > 0.0f && mrg * mrg > tau_f * 1.0001f) break;
    for (int dz = -r; dz <= r; ++dz)
      for (int dy = -r; dy <= r; ++dy) {
        if (abs(dz) == r || abs(dy) == r) {
          scan_range(qcy + dy, qcz + dz, qcx - r, qcx + r);
        } else {
          scan_range(qcy + dy, qcz + dz, qcx - r, qcx - r);
          scan_range(qcy + dy, qcz + dz, qcx + r, qcx + r);
        }
      }
  }
  if (qn > 0) drain();

  if (lane < MARGIN) rid[wv][lane] = (int)(uint32_t)(stp[wv][lane] & 0xFFFFFFFFull);
  __syncthreads();

  // ---- exact f64 re-rank of 12 candidates (identical to R11-R13) ----
  const double xn = (double)xnf, yn = (double)ynf, zn = (double)znf;
  const double sqn = xn * xn + yn * yn + zn * zn;
  double myd2 = 0.0;
  int myid = 0;
  if (lane < MARGIN) {
    myid = rid[wv][lane];
    double gx = (double)sb[myid], gy = (double)sb[NPTS + myid], gz = (double)sb[2 * NPTS + myid];
    double gsq = gx * gx + gy * gy + gz * gz;
    double dot = xn * gx + yn * gy + zn * gz;
    double d2 = sqn + gsq - 2.0 * dot;
    if (d2 < 0.0) d2 = 0.0;
    myd2 = d2;
    rd2[wv][lane] = d2;
  }
  __syncthreads();
  if (lane < MARGIN) {
    int rk = 0;
    for (int m = 0; m < MARGIN; ++m) {
      double dm = rd2[wv][m];
      rk += (dm < myd2) || (dm == myd2 && rid[wv][m] < myid);
    }
    if (rk < KNN) snbr[wv][rk] = myid;
  }
  __syncthreads();

  // ---- phase 2 (identical to rounds 8-13) ----
  const double txn = (double)tb[n], tyn = (double)tb[NPTS + n], tzn = (double)tb[2 * NPTS + n];
  const int p = lane;
  double loss = 0.0, reg = 0.0;
  if (p < NPAIR) {
    int g1 = snbr[wv][dCOMB_A[p]];
    int g2 = snbr[wv][dCOMB_B[p]];

    double ax = (double)sb[g1] - xn, ay = (double)sb[NPTS + g1] - yn, az = (double)sb[2 * NPTS + g1] - zn;
    double bx = (double)sb[g2] - xn, by = (double)sb[NPTS + g2] - yn, bz = (double)sb[2 * NPTS + g2] - zn;
    double cx = ay * bz - az * by;
    double cy = az * bx - ax * bz;
    double cz = ax * by - ay * bx;
    double s  = cx * cx + cy * cy + cz * cz;
    double a_s = (s > 0.0) ? 0.5 * sqrt(s) : 0.0;

    double ux = (double)tb[g1] - txn, uy = (double)tb[NPTS + g1] - tyn, uz = (double)tb[2 * NPTS + g1] - tzn;
    double vx = (double)tb[g2] - txn, vy = (double)tb[NPTS + g2] - tyn, vz = (double)tb[2 * NPTS + g2] - tzn;
    double wx = uy * vz - uz * vy;
    double wy = uz * vx - ux * vz;
    double wz = ux * vy - uy * vx;
    double t2 = wx * wx + wy * wy + wz * wz;
    double a_t = (t2 > 0.0) ? 0.5 * sqrt(t2) : 0.0;

    double ate = a_t + EPSD;
    double d   = a_s - ate;
    double numer = (EPSD * EPSD + EPSD * EPSD) + d * d;
    double denom = (EPSD + EPSD) + (a_s + ate);
    loss = numer / denom;
    reg  = sqrt(numer);
    lsA[wv][p] = loss;
  }
  __syncthreads();

  if (p < NPAIR) {
    int rk = 0;
    for (int m = 0; m < NPAIR; ++m) {
      double lm = lsA[wv][m];
      rk += (lm < loss) || (lm == loss && m < p);
    }
    lsB[wv][rk] = loss;
  }
  __syncthreads();
  double tot2 = 0.0;
  if (p < NPAIR) {
    tot2 = lsB[wv][p] + 0.1 * reg;
    lsA[wv][p] = tot2;
  }
  __syncthreads();
  if (p < NPAIR) {
    int rk = 0;
    for (int m = 0; m < NPAIR; ++m) {
      double tm = lsA[wv][m];
      rk += (tm < tot2) || (tm == tot2 && m < p);
    }
    if (rk == (NPAIR - 1) / 2) smed[wv] = tot2;
  }
  __syncthreads();
  double med = smed[wv];
  if (p < KNN) {
    double t = (tot2 > 3.0 * med) ? 0.0 : tot2;
    ssum[wv][p] = sqrt(t + EPSD);
  }
  __syncthreads();
  if (lane == 0) {
    double sum = 0.0;
#pragma unroll
    for (int q = 0; q < KNN; ++q) sum += ssum[wv][q];
    mean_out[b * NPTS + n] = (float)(sum / 10.0);
  }
}

// ---------------- fallback: R11 full-scan kernels ----------------
__global__ __launch_bounds__(256) void pack_pts(const float* __restrict__ src,
                                                float4* __restrict__ pk) {
  int i = blockIdx.x * 256 + threadIdx.x;
  int b = i >> 13, p = i & (NPTS - 1);
  const float* sb = src + (size_t)b * 3 * NPTS;
  float x = sb[p], y = sb[NPTS + p], z = sb[2 * NPTS + p];
  pk[i] = make_float4(x, y, z, x * x + y * y + z * z);
}

template <bool PACKED>
__global__ __launch_bounds__(256) void gfm_wave(const float* __restrict__ src,
                                                const float* __restrict__ tgt,
                                                const float4* __restrict__ pk,
                                                float* __restrict__ mean_out) {
  __shared__ float4   s4[TILE];
  __shared__ uint64_t sqq[4][QSZ];
  __shared__ uint64_t stp[4][MARGIN];
  __shared__ double lsA[4][NPAIR];
  __shared__ double lsB[4][NPAIR];
  __shared__ double smed[4];
  __shared__ double ssum[4][KNN];
  __shared__ double rd2[4][MARGIN];
  __shared__ int    rid[4][MARGIN];
  __shared__ int    snbr[4][KNN];

  const int tid  = threadIdx.x;
  const int wv   = tid >> 6;
  const int lane = tid & 63;
  const int b    = blockIdx.x >> 11;
  const int n    = ((blockIdx.x & 2047) << 2) | wv;

  const float* __restrict__ sb = src + (size_t)b * 3 * NPTS;
  const float* __restrict__ tb = tgt + (size_t)b * 3 * NPTS;

  const float xnf = sb[n], ynf = sb[NPTS + n], znf = sb[2 * NPTS + n];
  const float sqnf = xnf * xnf + ynf * ynf + znf * znf;

  if (lane < MARGIN) stp[wv][lane] = ~0ull;
  __builtin_amdgcn_wave_barrier();
  float tau_f = __builtin_inff();
  int qn = 0;

  auto drain = [&]() {
    if (lane < MARGIN) sqq[wv][qn + lane] = stp[wv][lane];
    __builtin_amdgcn_wave_barrier();
    const int tot = qn + MARGIN;
    uint64_t k0 = (lane < tot) ? sqq[wv][lane] : ~0ull;
    uint64_t k1 = (lane + 64 < tot) ? sqq[wv][lane + 64] : ~0ull;
    int r0 = 0, r1 = 0;
    for (int m = 0; m < tot; ++m) {
      uint64_t km = sqq[wv][m];
      r0 += (km < k0);
      r1 += (km < k1);
    }
    __builtin_amdgcn_wave_barrier();
    if (lane < tot && r0 < MARGIN) stp[wv][r0] = k0;
    if (lane + 64 < tot && r1 < MARGIN) stp[wv][r1] = k1;
    __builtin_amdgcn_wave_barrier();
    tau_f = __uint_as_float((uint32_t)(stp[wv][MARGIN - 1] >> 32));
    qn = 0;
  };

  for (int t0 = 0; t0 < NPTS; t0 += TILE) {
    __syncthreads();
    if (PACKED) {
      const float4* __restrict__ g = pk + (size_t)b * NPTS + t0;
#pragma unroll
      for (int r = 0; r < TILE / 256; ++r) {
        int i = tid + r * 256;
        s4[i] = g[i];
      }
    } else {
#pragma unroll
      for (int r = 0; r < TILE / 256; ++r) {
        int i = tid + r * 256;
        float x = sb[t0 + i], y = sb[NPTS + t0 + i], z = sb[2 * NPTS + t0 + i];
        s4[i] = make_float4(x, y, z, x * x + y * y + z * z);
      }
    }
    __syncthreads();
#pragma unroll 2
    for (int r = 0; r < TILE / 64; ++r) {
      int j = lane + (r << 6);
      float4 c = s4[j];
      float dot = fmaf(xnf, c.x, fmaf(ynf, c.y, znf * c.z));
      float d2 = fmaxf(fmaf(-2.0f, dot, sqnf + c.w), 0.0f);
      bool pred = d2 <= tau_f;
      uint64_t mask = __ballot(pred);
      if (mask) {
        uint64_t key = ((uint64_t)__float_as_uint(d2) << 32) | (uint32_t)(t0 + j);
        int below = __builtin_amdgcn_mbcnt_hi((uint32_t)(mask >> 32),
                     __builtin_amdgcn_mbcnt_lo((uint32_t)mask, 0));
        if (pred) sqq[wv][qn + below] = key;
        __builtin_amdgcn_wave_barrier();
        qn += __popcll(mask);
        if (qn >= DRAIN_AT) drain();
      }
    }
  }
  if (qn > 0) drain();

  if (lane < MARGIN) rid[wv][lane] = (int)(uint32_t)(stp[wv][lane] & 0xFFFFFFFFull);
  __syncthreads();

  const double xn = (double)xnf, yn = (double)ynf, zn = (double)znf;
  const double sqn = xn * xn + yn * yn + zn * zn;
  double myd2 = 0.0;
  int myid = 0;
  if (lane < MARGIN) {
    myid = rid[wv][lane];
    double gx = (double)sb[myid], gy = (double)sb[NPTS + myid], gz = (double)sb[2 * NPTS + myid];
    double gsq = gx * gx + gy * gy + gz * gz;
    double dot = xn * gx + yn * gy + zn * gz;
    double d2 = sqn + gsq - 2.0 * dot;
    if (d2 < 0.0) d2 = 0.0;
    myd2 = d2;
    rd2[wv][lane] = d2;
  }
  __syncthreads();
  if (lane < MARGIN) {
    int rk = 0;
    for (int m = 0; m < MARGIN; ++m) {
      double dm = rd2[wv][m];
      rk += (dm < myd2) || (dm == myd2 && rid[wv][m] < myid);
    }
    if (rk < KNN) snbr[wv][rk] = myid;
  }
  __syncthreads();

  const double txn = (double)tb[n], tyn = (double)tb[NPTS + n], tzn = (double)tb[2 * NPTS + n];
  const int p = lane;
  double loss = 0.0, reg = 0.0;
  if (p < NPAIR) {
    int g1 = snbr[wv][dCOMB_A[p]];
    int g2 = snbr[wv][dCOMB_B[p]];

    double ax = (double)sb[g1] - xn, ay = (double)sb[NPTS + g1] - yn, az = (double)sb[2 * NPTS + g1] - zn;
    double bx = (double)sb[g2] - xn, by = (double)sb[NPTS + g2] - yn, bz = (double)sb[2 * NPTS + g2] - zn;
    double cx = ay * bz - az * by;
    double cy = az * bx - ax * bz;
    double cz = ax * by - ay * bx;
    double s  = cx * cx + cy * cy + cz * cz;
    double a_s = (s > 0.0) ? 0.5 * sqrt(s) : 0.0;

    double ux = (double)tb[g1] - txn, uy = (double)tb[NPTS + g1] - tyn, uz = (double)tb[2 * NPTS + g1] - tzn;
    double vx = (double)tb[g2] - txn, vy = (double)tb[NPTS + g2] - tyn, vz = (double)tb[2 * NPTS + g2] - tzn;
    double wx = uy * vz - uz * vy;
    double wy = uz * vx - ux * vz;
    double wz = ux * vy - uy * vx;
    double t2 = wx * wx + wy * wy + wz * wz;
    double a_t = (t2 > 0.0) ? 0.5 * sqrt(t2) : 0.0;

    double ate = a_t + EPSD;
    double d   = a_s - ate;
    double numer = (EPSD * EPSD + EPSD * EPSD) + d * d;
    double denom = (EPSD + EPSD) + (a_s + ate);
    loss = numer / denom;
    reg  = sqrt(numer);
    lsA[wv][p] = loss;
  }
  __syncthreads();

  if (p < NPAIR) {
    int rk = 0;
    for (int m = 0; m < NPAIR; ++m) {
      double lm = lsA[wv][m];
      rk += (lm < loss) || (lm == loss && m < p);
    }
    lsB[wv][rk] = loss;
  }
  __syncthreads();
  double tot2 = 0.0;
  if (p < NPAIR) {
    tot2 = lsB[wv][p] + 0.1 * reg;
    lsA[wv][p] = tot2;
  }
  __syncthreads();
  if (p < NPAIR) {
    int rk = 0;
    for (int m = 0; m < NPAIR; ++m) {
      double tm = lsA[wv][m];
      rk += (tm < tot2) || (tm == tot2 && m < p);
    }
    if (rk == (NPAIR - 1) / 2) smed[wv] = tot2;
  }
  __syncthreads();
  double med = smed[wv];
  if (p < KNN) {
    double t = (tot2 > 3.0 * med) ? 0.0 : tot2;
    ssum[wv][p] = sqrt(t + EPSD);
  }
  __syncthreads();
  if (lane == 0) {
    double sum = 0.0;
#pragma unroll
    for (int q = 0; q < KNN; ++q) sum += ssum[wv][q];
    mean_out[b * NPTS + n] = (float)(sum / 10.0);
  }
}

// ---------------- finalize (unchanged) ----------------
__global__ __launch_bounds__(1024) void gfm_finalize(float* __restrict__ buf) {
  __shared__ float red[16];
  const int b = blockIdx.x;
  const int tid = threadIdx.x;
  float* __restrict__ mb = buf + b * NPTS;

  float v[8];
  float mn = 3.4e38f;
#pragma unroll
  for (int r = 0; r < 8; ++r) {
    v[r] = mb[tid + r * 1024];
    mn = fminf(mn, v[r]);
  }
#pragma unroll
  for (int s = 32; s >= 1; s >>= 1)
    mn = fminf(mn, __shfl_xor(mn, s, 64));
  if ((tid & 63) == 0) red[tid >> 6] = mn;
  __syncthreads();
  mn = red[0];
#pragma unroll
  for (int q = 1; q < 16; ++q) mn = fminf(mn, red[q]);
  __syncthreads();

#pragma unroll
  for (int r = 0; r < 8; ++r) {
    double t = (double)v[r] - (double)mn;
    double w = 2.0 / (1.0 + exp(20.0 * t));
    mb[tid + r * 1024] = (w > 0.5) ? 1.0f : 0.0f;
  }
}

extern "C" void kernel_launch(void* const* d_in, const int* in_sizes, int n_in,
                              void* d_out, int out_size, void* d_ws, size_t ws_size,
                              hipStream_t stream) {
  const float* src = (const float*)d_in[0];
  const float* tgt = (const float*)d_in[1];
  float* out = (float*)d_out;

  const size_t nP = (size_t)NBATCH * NPTS;
  const size_t sz_pts  = nP * sizeof(float4);                 // 512 KiB
  const size_t sz_oidx = nP * sizeof(uint32_t);               // 128 KiB
  const size_t sz_cs   = (size_t)NBATCH * (NCELL + 1) * 4;    // ~43 KiB
  const size_t sz_cc   = (size_t)NBATCH * NCELL * 4;          // ~43 KiB
  const size_t need = sz_pts + sz_oidx + sz_cs + sz_cc;

  if (ws_size >= need) {
    char* w = (char*)d_ws;
    float4*   pts = (float4*)w;
    uint32_t* oid = (uint32_t*)(w + sz_pts);
    uint32_t* cst = (uint32_t*)(w + sz_pts + sz_oidx);
    uint32_t* ccu = (uint32_t*)(w + sz_pts + sz_oidx + sz_cs);

    zero_cells<<<(NBATCH * NCELL + 255) / 256, 256, 0, stream>>>(ccu);
    grid_count<<<(int)(nP / 256), 256, 0, stream>>>(src, ccu);
    grid_scan<<<NBATCH, 1024, 0, stream>>>(ccu, cst);
    grid_scatter<<<(int)(nP / 256), 256, 0, stream>>>(src, ccu, pts, oid);
    gfm_grid<<<NBATCH * NPTS / 4, 256, 0, stream>>>(src, tgt, pts, oid, cst, out);
  } else if (ws_size >= sz_pts) {
    float4* pk = (float4*)d_ws;
    pack_pts<<<(int)(nP / 256), 256, 0, stream>>>(src, pk);
    gfm_wave<true><<<NBATCH * NPTS / 4, 256, 0, stream>>>(src, tgt, pk, out);
  } else {
    gfm_wave<false><<<NBATCH * NPTS / 4, 256, 0, stream>>>(src, tgt, nullptr, out);
  }
  gfm_finalize<<<NBATCH, 1024, 0, stream>>>(out);
}

// Round 15
// 148.342 us; speedup vs baseline: 2.3157x; 1.0417x over previous
//
#include <hip/hip_runtime.h>
#include <cstdint>
#include <cstddef>

#define NPTS 8192
#define NBATCH 4
#define KNN 10
#define NPAIR 45
#define TILE 512
#define MARGIN 12
#define QSZ 96
#define DRAIN_AT 16
#define EPSD 1e-6
#define GRID 14
#define NCELL (GRID*GRID*GRID)
#define HCELL 0.7f
#define ORG (-4.9f)

__device__ __constant__ int dCOMB_A[NPAIR] = {
  0,0,0,0,0,0,0,0,0, 1,1,1,1,1,1,1,1, 2,2,2,2,2,2,2,
  3,3,3,3,3,3, 4,4,4,4,4, 5,5,5,5, 6,6,6, 7,7, 8};
__device__ __constant__ int dCOMB_B[NPAIR] = {
  1,2,3,4,5,6,7,8,9, 2,3,4,5,6,7,8,9, 3,4,5,6,7,8,9,
  4,5,6,7,8,9, 5,6,7,8,9, 6,7,8,9, 7,8,9, 8,9, 9};

__device__ __forceinline__ void cell_coords(float x, float y, float z,
                                            int& cx, int& cy, int& cz) {
  cx = (int)floorf((x - ORG) * (1.0f / HCELL));
  cy = (int)floorf((y - ORG) * (1.0f / HCELL));
  cz = (int)floorf((z - ORG) * (1.0f / HCELL));
  cx = min(max(cx, 0), GRID - 1);
  cy = min(max(cy, 0), GRID - 1);
  cz = min(max(cz, 0), GRID - 1);
}

// ---------------- fused grid build: one block per batch ----------------
// count (LDS atomics) -> exclusive scan (LDS) -> scatter, points cached in regs.
__global__ __launch_bounds__(1024) void grid_build(const float* __restrict__ src,
                                                   float4* __restrict__ pts,
                                                   uint32_t* __restrict__ oidx,
                                                   uint32_t* __restrict__ cstart) {
  __shared__ uint32_t scnt[NCELL];   // counts -> cursors (10976 B)
  __shared__ uint32_t swv[16];
  const int b = blockIdx.x;
  const int tid = threadIdx.x, lane = tid & 63, wid = tid >> 6;
  const float* __restrict__ sb = src + (size_t)b * 3 * NPTS;

  for (int i = tid; i < NCELL; i += 1024) scnt[i] = 0;
  __syncthreads();

  float px[8], py[8], pz[8];
  int pc[8];
#pragma unroll
  for (int k = 0; k < 8; ++k) {
    int p = tid + k * 1024;
    float x = sb[p], y = sb[NPTS + p], z = sb[2 * NPTS + p];
    px[k] = x; py[k] = y; pz[k] = z;
    int cx, cy, cz;
    cell_coords(x, y, z, cx, cy, cz);
    pc[k] = ((cz * GRID) + cy) * GRID + cx;
    atomicAdd(&scnt[pc[k]], 1u);
  }
  __syncthreads();

  // exclusive scan of scnt -> global cstart + LDS cursors (same math as R13/14)
  const int i0 = tid * 4;   // 4096 >= NCELL
  uint32_t v[4], ts = 0;
#pragma unroll
  for (int k = 0; k < 4; ++k) {
    v[k] = (i0 + k < NCELL) ? scnt[i0 + k] : 0u;
    ts += v[k];
  }
  uint32_t x = ts;
#pragma unroll
  for (int off = 1; off < 64; off <<= 1) {
    uint32_t y = __shfl_up(x, off, 64);
    if (lane >= off) x += y;
  }
  if (lane == 63) swv[wid] = x;
  __syncthreads();
  uint32_t wpre = 0, bsum = 0;
  for (int w = 0; w < 16; ++w) { uint32_t s = swv[w]; bsum += s; if (w < wid) wpre += s; }
  uint32_t excl = wpre + (x - ts);
#pragma unroll
  for (int k = 0; k < 4; ++k) {
    if (i0 + k < NCELL) {
      cstart[b * (NCELL + 1) + i0 + k] = excl;
      scnt[i0 + k] = excl;            // cursor
      excl += v[k];
    }
  }
  if (tid == 0) cstart[b * (NCELL + 1) + NCELL] = bsum;   // = NPTS
  __syncthreads();

  // scatter from registers
#pragma unroll
  for (int k = 0; k < 8; ++k) {
    uint32_t pos = atomicAdd(&scnt[pc[k]], 1u);
    pts[(b << 13) + pos]  = make_float4(px[k], py[k], pz[k],
                                        px[k] * px[k] + py[k] * py[k] + pz[k] * pz[k]);
    oidx[(b << 13) + pos] = (uint32_t)(tid + k * 1024);
  }
}

// ---------------- main: sorted-order queries, row walk + pruning ----------------
__global__ __launch_bounds__(256) void gfm_grid(const float* __restrict__ src,
                                                const float* __restrict__ tgt,
                                                const float4* __restrict__ pts,
                                                const uint32_t* __restrict__ oidx,
                                                const uint32_t* __restrict__ cstart,
                                                float* __restrict__ mean_out) {
  __shared__ uint64_t sqq[4][QSZ];
  __shared__ uint64_t stp[4][MARGIN];
  __shared__ double lsA[4][NPAIR];
  __shared__ double lsB[4][NPAIR];
  __shared__ double smed[4];
  __shared__ double ssum[4][KNN];
  __shared__ double rd2[4][MARGIN];
  __shared__ int    rid[4][MARGIN];
  __shared__ int    snbr[4][KNN];

  const int tid  = threadIdx.x;
  const int wv   = tid >> 6;
  const int lane = tid & 63;
  const int b    = blockIdx.x >> 11;
  const int pos  = ((blockIdx.x & 2047) << 2) | wv;   // cell-sorted position

  const float* __restrict__ sb = src + (size_t)b * 3 * NPTS;
  const float* __restrict__ tb = tgt + (size_t)b * 3 * NPTS;
  const float4* __restrict__ ppts = pts + ((size_t)b << 13);
  const uint32_t* __restrict__ poid = oidx + ((size_t)b << 13);
  const uint32_t* __restrict__ cs = cstart + (size_t)b * (NCELL + 1);

  const float4 q4 = ppts[pos];
  const int n = (int)poid[pos];                       // original point id
  const float xnf = q4.x, ynf = q4.y, znf = q4.z;
  const float sqnf = q4.w;

  int qcx, qcy, qcz;
  cell_coords(xnf, ynf, znf, qcx, qcy, qcz);
  float lox = ORG + qcx * HCELL, loy = ORG + qcy * HCELL, loz = ORG + qcz * HCELL;
  float dqx = fmaxf(fmaxf(lox - xnf, xnf - (lox + HCELL)), 0.0f);
  float dqy = fmaxf(fmaxf(loy - ynf, ynf - (loy + HCELL)), 0.0f);
  float dqz = fmaxf(fmaxf(loz - znf, znf - (loz + HCELL)), 0.0f);
  const float deltaq = sqrtf(dqx * dqx + dqy * dqy + dqz * dqz);

  if (lane < MARGIN) stp[wv][lane] = ~0ull;
  __builtin_amdgcn_wave_barrier();
  float tau_f = __builtin_inff();
  int qn = 0;

  auto drain = [&]() {
    if (lane < MARGIN) sqq[wv][qn + lane] = stp[wv][lane];
    __builtin_amdgcn_wave_barrier();
    const int tot = qn + MARGIN;
    uint64_t k0 = (lane < tot) ? sqq[wv][lane] : ~0ull;
    uint64_t k1 = (lane + 64 < tot) ? sqq[wv][lane + 64] : ~0ull;
    int r0 = 0, r1 = 0;
    for (int m = 0; m < tot; ++m) {
      uint64_t km = sqq[wv][m];
      r0 += (km < k0);
      r1 += (km < k1);
    }
    __builtin_amdgcn_wave_barrier();
    if (lane < tot && r0 < MARGIN) stp[wv][r0] = k0;
    if (lane + 64 < tot && r1 < MARGIN) stp[wv][r1] = k1;
    __builtin_amdgcn_wave_barrier();
    tau_f = __uint_as_float((uint32_t)(stp[wv][MARGIN - 1] >> 32));
    qn = 0;
  };

  auto scan_range = [&](int cy, int cz, int cx0, int cx1) {
    if (cy < 0 || cy >= GRID || cz < 0 || cz >= GRID) return;
    cx0 = max(cx0, 0); cx1 = min(cx1, GRID - 1);
    if (cx0 > cx1) return;
    float bx0 = ORG + cx0 * HCELL, bx1 = ORG + (cx1 + 1) * HCELL;
    float by0 = ORG + cy * HCELL,  by1 = by0 + HCELL;
    float bz0 = ORG + cz * HCELL,  bz1 = bz0 + HCELL;
    float ddx = fmaxf(fmaxf(bx0 - xnf, xnf - bx1), 0.0f);
    float ddy = fmaxf(fmaxf(by0 - ynf, ynf - by1), 0.0f);
    float ddz = fmaxf(fmaxf(bz0 - znf, znf - bz1), 0.0f);
    float rowmin = ddx * ddx + ddy * ddy + ddz * ddz;
    if (rowmin > tau_f * 1.001f + 1e-5f) return;   // provably all-beyond-tau
    uint32_t c0 = (uint32_t)(((cz * GRID) + cy) * GRID + cx0);
    uint32_t st = cs[c0];
    uint32_t en = cs[c0 + (uint32_t)(cx1 - cx0) + 1];
    for (uint32_t base = st; base < en; base += 64) {
      uint32_t pp = base + (uint32_t)lane;
      bool act = pp < en;
      float d2 = 0.0f;
      bool pred = false;
      if (act) {
        float4 c4 = ppts[pp];
        float dot = fmaf(xnf, c4.x, fmaf(ynf, c4.y, znf * c4.z));
        d2 = fmaxf(fmaf(-2.0f, dot, sqnf + c4.w), 0.0f);
        pred = d2 <= tau_f;
      }
      uint64_t m2 = __ballot(pred);
      if (m2) {
        int below = __builtin_amdgcn_mbcnt_hi((uint32_t)(m2 >> 32),
                     __builtin_amdgcn_mbcnt_lo((uint32_t)m2, 0));
        if (pred) {
          uint64_t key = ((uint64_t)__float_as_uint(d2) << 32) | (uint64_t)poid[pp];
          sqq[wv][qn + below] = key;
        }
        __builtin_amdgcn_wave_barrier();
        qn += __popcll(m2);
        if (qn >= DRAIN_AT) drain();
      }
    }
  };

  // center row FIRST (tightens tau immediately), then remaining 8 box-1 rows
  scan_range(qcy, qcz, qcx - 1, qcx + 1);
#pragma unroll
  for (int dz = -1; dz <= 1; ++dz)
#pragma unroll
    for (int dy = -1; dy <= 1; ++dy)
      if (!(dy == 0 && dz == 0))
        scan_range(qcy + dy, qcz + dz, qcx - 1, qcx + 1);

  // shells r>=2 (rare)
  for (int r = 2; r < GRID; ++r) {
    float mrg = (float)(r - 1) * HCELL - deltaq;
    if (mrg > 0.0f && mrg * mrg > tau_f * 1.0001f) break;
    for (int dz = -r; dz <= r; ++dz)
      for (int dy = -r; dy <= r; ++dy) {
        if (abs(dz) == r || abs(dy) == r) {
          scan_range(qcy + dy, qcz + dz, qcx - r, qcx + r);
        } else {
          scan_range(qcy + dy, qcz + dz, qcx - r, qcx - r);
          scan_range(qcy + dy, qcz + dz, qcx + r, qcx + r);
        }
      }
  }
  if (qn > 0) drain();

  if (lane < MARGIN) rid[wv][lane] = (int)(uint32_t)(stp[wv][lane] & 0xFFFFFFFFull);
  __syncthreads();

  // ---- exact f64 re-rank of 12 candidates (identical to R11-R14) ----
  const double xn = (double)xnf, yn = (double)ynf, zn = (double)znf;
  const double sqn = xn * xn + yn * yn + zn * zn;
  double myd2 = 0.0;
  int myid = 0;
  if (lane < MARGIN) {
    myid = rid[wv][lane];
    double gx = (double)sb[myid], gy = (double)sb[NPTS + myid], gz = (double)sb[2 * NPTS + myid];
    double gsq = gx * gx + gy * gy + gz * gz;
    double dot = xn * gx + yn * gy + zn * gz;
    double d2 = sqn + gsq - 2.0 * dot;
    if (d2 < 0.0) d2 = 0.0;
    myd2 = d2;
    rd2[wv][lane] = d2;
  }
  __syncthreads();
  if (lane < MARGIN) {
    int rk = 0;
    for (int m = 0; m < MARGIN; ++m) {
      double dm = rd2[wv][m];
      rk += (dm < myd2) || (dm == myd2 && rid[wv][m] < myid);
    }
    if (rk < KNN) snbr[wv][rk] = myid;
  }
  __syncthreads();

  // ---- phase 2 (identical to rounds 8-14) ----
  const double txn = (double)tb[n], tyn = (double)tb[NPTS + n], tzn = (double)tb[2 * NPTS + n];
  const int p = lane;
  double loss = 0.0, reg = 0.0;
  if (p < NPAIR) {
    int g1 = snbr[wv][dCOMB_A[p]];
    int g2 = snbr[wv][dCOMB_B[p]];

    double ax = (double)sb[g1] - xn, ay = (double)sb[NPTS + g1] - yn, az = (double)sb[2 * NPTS + g1] - zn;
    double bx = (double)sb[g2] - xn, by = (double)sb[NPTS + g2] - yn, bz = (double)sb[2 * NPTS + g2] - zn;
    double cx = ay * bz - az * by;
    double cy = az * bx - ax * bz;
    double cz = ax * by - ay * bx;
    double s  = cx * cx + cy * cy + cz * cz;
    double a_s = (s > 0.0) ? 0.5 * sqrt(s) : 0.0;

    double ux = (double)tb[g1] - txn, uy = (double)tb[NPTS + g1] - tyn, uz = (double)tb[2 * NPTS + g1] - tzn;
    double vx = (double)tb[g2] - txn, vy = (double)tb[NPTS + g2] - tyn, vz = (double)tb[2 * NPTS + g2] - tzn;
    double wx = uy * vz - uz * vy;
    double wy = uz * vx - ux * vz;
    double wz = ux * vy - uy * vx;
    double t2 = wx * wx + wy * wy + wz * wz;
    double a_t = (t2 > 0.0) ? 0.5 * sqrt(t2) : 0.0;

    double ate = a_t + EPSD;
    double d   = a_s - ate;
    double numer = (EPSD * EPSD + EPSD * EPSD) + d * d;
    double denom = (EPSD + EPSD) + (a_s + ate);
    loss = numer / denom;
    reg  = sqrt(numer);
    lsA[wv][p] = loss;
  }
  __syncthreads();

  if (p < NPAIR) {
    int rk = 0;
    for (int m = 0; m < NPAIR; ++m) {
      double lm = lsA[wv][m];
      rk += (lm < loss) || (lm == loss && m < p);
    }
    lsB[wv][rk] = loss;
  }
  __syncthreads();
  double tot2 = 0.0;
  if (p < NPAIR) {
    tot2 = lsB[wv][p] + 0.1 * reg;
    lsA[wv][p] = tot2;
  }
  __syncthreads();
  if (p < NPAIR) {
    int rk = 0;
    for (int m = 0; m < NPAIR; ++m) {
      double tm = lsA[wv][m];
      rk += (tm < tot2) || (tm == tot2 && m < p);
    }
    if (rk == (NPAIR - 1) / 2) smed[wv] = tot2;
  }
  __syncthreads();
  double med = smed[wv];
  if (p < KNN) {
    double t = (tot2 > 3.0 * med) ? 0.0 : tot2;
    ssum[wv][p] = sqrt(t + EPSD);
  }
  __syncthreads();
  if (lane == 0) {
    double sum = 0.0;
#pragma unroll
    for (int q = 0; q < KNN; ++q) sum += ssum[wv][q];
    mean_out[b * NPTS + n] = (float)(sum / 10.0);
  }
}

// ---------------- fallback: R11 full-scan kernels ----------------
__global__ __launch_bounds__(256) void pack_pts(const float* __restrict__ src,
                                                float4* __restrict__ pk) {
  int i = blockIdx.x * 256 + threadIdx.x;
  int b = i >> 13, p = i & (NPTS - 1);
  const float* sb = src + (size_t)b * 3 * NPTS;
  float x = sb[p], y = sb[NPTS + p], z = sb[2 * NPTS + p];
  pk[i] = make_float4(x, y, z, x * x + y * y + z * z);
}

template <bool PACKED>
__global__ __launch_bounds__(256) void gfm_wave(const float* __restrict__ src,
                                                const float* __restrict__ tgt,
                                                const float4* __restrict__ pk,
                                                float* __restrict__ mean_out) {
  __shared__ float4   s4[TILE];
  __shared__ uint64_t sqq[4][QSZ];
  __shared__ uint64_t stp[4][MARGIN];
  __shared__ double lsA[4][NPAIR];
  __shared__ double lsB[4][NPAIR];
  __shared__ double smed[4];
  __shared__ double ssum[4][KNN];
  __shared__ double rd2[4][MARGIN];
  __shared__ int    rid[4][MARGIN];
  __shared__ int    snbr[4][KNN];

  const int tid  = threadIdx.x;
  const int wv   = tid >> 6;
  const int lane = tid & 63;
  const int b    = blockIdx.x >> 11;
  const int n    = ((blockIdx.x & 2047) << 2) | wv;

  const float* __restrict__ sb = src + (size_t)b * 3 * NPTS;
  const float* __restrict__ tb = tgt + (size_t)b * 3 * NPTS;

  const float xnf = sb[n], ynf = sb[NPTS + n], znf = sb[2 * NPTS + n];
  const float sqnf = xnf * xnf + ynf * ynf + znf * znf;

  if (lane < MARGIN) stp[wv][lane] = ~0ull;
  __builtin_amdgcn_wave_barrier();
  float tau_f = __builtin_inff();
  int qn = 0;

  auto drain = [&]() {
    if (lane < MARGIN) sqq[wv][qn + lane] = stp[wv][lane];
    __builtin_amdgcn_wave_barrier();
    const int tot = qn + MARGIN;
    uint64_t k0 = (lane < tot) ? sqq[wv][lane] : ~0ull;
    uint64_t k1 = (lane + 64 < tot) ? sqq[wv][lane + 64] : ~0ull;
    int r0 = 0, r1 = 0;
    for (int m = 0; m < tot; ++m) {
      uint64_t km = sqq[wv][m];
      r0 += (km < k0);
      r1 += (km < k1);
    }
    __builtin_amdgcn_wave_barrier();
    if (lane < tot && r0 < MARGIN) stp[wv][r0] = k0;
    if (lane + 64 < tot && r1 < MARGIN) stp[wv][r1] = k1;
    __builtin_amdgcn_wave_barrier();
    tau_f = __uint_as_float((uint32_t)(stp[wv][MARGIN - 1] >> 32));
    qn = 0;
  };

  for (int t0 = 0; t0 < NPTS; t0 += TILE) {
    __syncthreads();
    if (PACKED) {
      const float4* __restrict__ g = pk + (size_t)b * NPTS + t0;
#pragma unroll
      for (int r = 0; r < TILE / 256; ++r) {
        int i = tid + r * 256;
        s4[i] = g[i];
      }
    } else {
#pragma unroll
      for (int r = 0; r < TILE / 256; ++r) {
        int i = tid + r * 256;
        float x = sb[t0 + i], y = sb[NPTS + t0 + i], z = sb[2 * NPTS + t0 + i];
        s4[i] = make_float4(x, y, z, x * x + y * y + z * z);
      }
    }
    __syncthreads();
#pragma unroll 2
    for (int r = 0; r < TILE / 64; ++r) {
      int j = lane + (r << 6);
      float4 c = s4[j];
      float dot = fmaf(xnf, c.x, fmaf(ynf, c.y, znf * c.z));
      float d2 = fmaxf(fmaf(-2.0f, dot, sqnf + c.w), 0.0f);
      bool pred = d2 <= tau_f;
      uint64_t mask = __ballot(pred);
      if (mask) {
        uint64_t key = ((uint64_t)__float_as_uint(d2) << 32) | (uint32_t)(t0 + j);
        int below = __builtin_amdgcn_mbcnt_hi((uint32_t)(mask >> 32),
                     __builtin_amdgcn_mbcnt_lo((uint32_t)mask, 0));
        if (pred) sqq[wv][qn + below] = key;
        __builtin_amdgcn_wave_barrier();
        qn += __popcll(mask);
        if (qn >= DRAIN_AT) drain();
      }
    }
  }
  if (qn > 0) drain();

  if (lane < MARGIN) rid[wv][lane] = (int)(uint32_t)(stp[wv][lane] & 0xFFFFFFFFull);
  __syncthreads();

  const double xn = (double)xnf, yn = (double)ynf, zn = (double)znf;
  const double sqn = xn * xn + yn * yn + zn * zn;
  double myd2 = 0.0;
  int myid = 0;
  if (lane < MARGIN) {
    myid = rid[wv][lane];
    double gx = (double)sb[myid], gy = (double)sb[NPTS + myid], gz = (double)sb[2 * NPTS + myid];
    double gsq = gx * gx + gy * gy + gz * gz;
    double dot = xn * gx + yn * gy + zn * gz;
    double d2 = sqn + gsq - 2.0 * dot;
    if (d2 < 0.0) d2 = 0.0;
    myd2 = d2;
    rd2[wv][lane] = d2;
  }
  __syncthreads();
  if (lane < MARGIN) {
    int rk = 0;
    for (int m = 0; m < MARGIN; ++m) {
      double dm = rd2[wv][m];
      rk += (dm < myd2) || (dm == myd2 && rid[wv][m] < myid);
    }
    if (rk < KNN) snbr[wv][rk] = myid;
  }
  __syncthreads();

  const double txn = (double)tb[n], tyn = (double)tb[NPTS + n], tzn = (double)tb[2 * NPTS + n];
  const int p = lane;
  double loss = 0.0, reg = 0.0;
  if (p < NPAIR) {
    int g1 = snbr[wv][dCOMB_A[p]];
    int g2 = snbr[wv][dCOMB_B[p]];

    double ax = (double)sb[g1] - xn, ay = (double)sb[NPTS + g1] - yn, az = (double)sb[2 * NPTS + g1] - zn;
    double bx = (double)sb[g2] - xn, by = (double)sb[NPTS + g2] - yn, bz = (double)sb[2 * NPTS + g2] - zn;
    double cx = ay * bz - az * by;
    double cy = az * bx - ax * bz;
    double cz = ax * by - ay * bx;
    double s  = cx * cx + cy * cy + cz * cz;
    double a_s = (s > 0.0) ? 0.5 * sqrt(s) : 0.0;

    double ux = (double)tb[g1] - txn, uy = (double)tb[NPTS + g1] - tyn, uz = (double)tb[2 * NPTS + g1] - tzn;
    double vx = (double)tb[g2] - txn, vy = (double)tb[NPTS + g2] - tyn, vz = (double)tb[2 * NPTS + g2] - tzn;
    double wx = uy * vz - uz * vy;
    double wy = uz * vx - ux * vz;
    double wz = ux * vy - uy * vx;
    double t2 = wx * wx + wy * wy + wz * wz;
    double a_t = (t2 > 0.0) ? 0.5 * sqrt(t2) : 0.0;

    double ate = a_t + EPSD;
    double d   = a_s - ate;
    double numer = (EPSD * EPSD + EPSD * EPSD) + d * d;
    double denom = (EPSD + EPSD) + (a_s + ate);
    loss = numer / denom;
    reg  = sqrt(numer);
    lsA[wv][p] = loss;
  }
  __syncthreads();

  if (p < NPAIR) {
    int rk = 0;
    for (int m = 0; m < NPAIR; ++m) {
      double lm = lsA[wv][m];
      rk += (lm < loss) || (lm == loss && m < p);
    }
    lsB[wv][rk] = loss;
  }
  __syncthreads();
  double tot2 = 0.0;
  if (p < NPAIR) {
    tot2 = lsB[wv][p] + 0.1 * reg;
    lsA[wv][p] = tot2;
  }
  __syncthreads();
  if (p < NPAIR) {
    int rk = 0;
    for (int m = 0; m < NPAIR; ++m) {
      double tm = lsA[wv][m];
      rk += (tm < tot2) || (tm == tot2 && m < p);
    }
    if (rk == (NPAIR - 1) / 2) smed[wv] = tot2;
  }
  __syncthreads();
  double med = smed[wv];
  if (p < KNN) {
    double t = (tot2 > 3.0 * med) ? 0.0 : tot2;
    ssum[wv][p] = sqrt(t + EPSD);
  }
  __syncthreads();
  if (lane == 0) {
    double sum = 0.0;
#pragma unroll
    for (int q = 0; q < KNN; ++q) sum += ssum[wv][q];
    mean_out[b * NPTS + n] = (float)(sum / 10.0);
  }
}

// ---------------- finalize (unchanged) ----------------
__global__ __launch_bounds__(1024) void gfm_finalize(float* __restrict__ buf) {
  __shared__ float red[16];
  const int b = blockIdx.x;
  const int tid = threadIdx.x;
  float* __restrict__ mb = buf + b * NPTS;

  float v[8];
  float mn = 3.4e38f;
#pragma unroll
  for (int r = 0; r < 8; ++r) {
    v[r] = mb[tid + r * 1024];
    mn = fminf(mn, v[r]);
  }
#pragma unroll
  for (int s = 32; s >= 1; s >>= 1)
    mn = fminf(mn, __shfl_xor(mn, s, 64));
  if ((tid & 63) == 0) red[tid >> 6] = mn;
  __syncthreads();
  mn = red[0];
#pragma unroll
  for (int q = 1; q < 16; ++q) mn = fminf(mn, red[q]);
  __syncthreads();

#pragma unroll
  for (int r = 0; r < 8; ++r) {
    double t = (double)v[r] - (double)mn;
    double w = 2.0 / (1.0 + exp(20.0 * t));
    mb[tid + r * 1024] = (w > 0.5) ? 1.0f : 0.0f;
  }
}

extern "C" void kernel_launch(void* const* d_in, const int* in_sizes, int n_in,
                              void* d_out, int out_size, void* d_ws, size_t ws_size,
                              hipStream_t stream) {
  const float* src = (const float*)d_in[0];
  const float* tgt = (const float*)d_in[1];
  float* out = (float*)d_out;

  const size_t nP = (size_t)NBATCH * NPTS;
  const size_t sz_pts  = nP * sizeof(float4);                 // 512 KiB
  const size_t sz_oidx = nP * sizeof(uint32_t);               // 128 KiB
  const size_t sz_cs   = (size_t)NBATCH * (NCELL + 1) * 4;    // ~43 KiB
  const size_t need = sz_pts + sz_oidx + sz_cs;

  if (ws_size >= need) {
    char* w = (char*)d_ws;
    float4*   pts = (float4*)w;
    uint32_t* oid = (uint32_t*)(w + sz_pts);
    uint32_t* cst = (uint32_t*)(w + sz_pts + sz_oidx);

    grid_build<<<NBATCH, 1024, 0, stream>>>(src, pts, oid, cst);
    gfm_grid<<<NBATCH * NPTS / 4, 256, 0, stream>>>(src, tgt, pts, oid, cst, out);
  } else if (ws_size >= sz_pts) {
    float4* pk = (float4*)d_ws;
    pack_pts<<<(int)(nP / 256), 256, 0, stream>>>(src, pk);
    gfm_wave<true><<<NBATCH * NPTS / 4, 256, 0, stream>>>(src, tgt, pk, out);
  } else {
    gfm_wave<false><<<NBATCH * NPTS / 4, 256, 0, stream>>>(src, tgt, nullptr, out);
  }
  gfm_finalize<<<NBATCH, 1024, 0, stream>>>(out);
}